// Round 1
// baseline (4345.920 us; speedup 1.0000x reference)
//
#include <hip/hip_runtime.h>
#include <hip/hip_bf16.h>

// Problem constants
#define BB 4
#define TT 32
#define LL 64
#define DD 768
#define NHEAD 12
#define DH 64
#define DFF 2048
#define NLAYERS 2
#define ROWS (BB*TT*LL)      // 8192
#define BTN  (BB*TT)         // 128

// ---------------------------------------------------------------------------
// edu = mean over L of token_embeddings  : (B,T,D)
// one thread per (bt,d); loop over l is coalesced in d across the wave
__global__ __launch_bounds__(256) void edu_mean_kernel(
    const float* __restrict__ te, float* __restrict__ edu)
{
    int idx = blockIdx.x * 256 + threadIdx.x;       // bt*768 + d
    int bt = idx / DD;
    int d  = idx - bt * DD;
    const float* p = te + ((size_t)bt * LL) * DD + d;
    float s = 0.f;
#pragma unroll
    for (int l = 0; l < LL; ++l) s += p[(size_t)l * DD];
    edu[idx] = s * (1.0f / (float)LL);
}

// ---------------------------------------------------------------------------
// Generic fp32 GEMM:  C[M,N] = A[M,K] @ B[N,K]^T (+bias) (opt relu)
// BM=BN=64, BK=16, 256 threads, 4x4 micro-tile per thread.
// Requires M%64==0, N%64==0, K%16==0.
#define GBM 64
#define GBN 64
#define GBK 16
__global__ __launch_bounds__(256) void gemm_abt_kernel(
    const float* __restrict__ A, const float* __restrict__ B,
    const float* __restrict__ bias, float* __restrict__ C,
    int M, int N, int K, int relu)
{
    __shared__ float As[GBM][GBK + 1];
    __shared__ float Bs[GBN][GBK + 1];
    const int bm = blockIdx.y * GBM;
    const int bn = blockIdx.x * GBN;
    const int tid = threadIdx.x;
    const int tx = tid & 15;          // 0..15  (cols)
    const int ty = tid >> 4;          // 0..15  (rows)
    const int lr = tid >> 2;          // 0..63  load row
    const int lc = (tid & 3) << 2;    // 0,4,8,12 load col

    float acc[4][4] = {};

    for (int k0 = 0; k0 < K; k0 += GBK) {
        float4 va = *reinterpret_cast<const float4*>(A + (size_t)(bm + lr) * K + k0 + lc);
        float4 vb = *reinterpret_cast<const float4*>(B + (size_t)(bn + lr) * K + k0 + lc);
        As[lr][lc + 0] = va.x; As[lr][lc + 1] = va.y;
        As[lr][lc + 2] = va.z; As[lr][lc + 3] = va.w;
        Bs[lr][lc + 0] = vb.x; Bs[lr][lc + 1] = vb.y;
        Bs[lr][lc + 2] = vb.z; Bs[lr][lc + 3] = vb.w;
        __syncthreads();
#pragma unroll
        for (int kk = 0; kk < GBK; ++kk) {
            float a[4], b[4];
#pragma unroll
            for (int i = 0; i < 4; ++i) a[i] = As[ty * 4 + i][kk];
#pragma unroll
            for (int j = 0; j < 4; ++j) b[j] = Bs[tx * 4 + j][kk];
#pragma unroll
            for (int i = 0; i < 4; ++i)
#pragma unroll
                for (int j = 0; j < 4; ++j)
                    acc[i][j] = fmaf(a[i], b[j], acc[i][j]);
        }
        __syncthreads();
    }

#pragma unroll
    for (int i = 0; i < 4; ++i) {
        int r = bm + ty * 4 + i;
#pragma unroll
        for (int j = 0; j < 4; ++j) {
            int cn = bn + tx * 4 + j;
            float v = acc[i][j];
            if (bias) v += bias[cn];
            if (relu) v = fmaxf(v, 0.f);
            C[(size_t)r * N + cn] = v;
        }
    }
}

// ---------------------------------------------------------------------------
// SAUTE context (in place on x = tok):
//   x[row,:] += sum_u mask(b,t,u) * (v[b,u,:] . x[row,:]) * k[b,u,:]
// one block per row (b,t,l). 256 threads.
__global__ __launch_bounds__(256) void saute_kernel(
    float* __restrict__ x,
    const float* __restrict__ kmat,   // (B*T, D)
    const float* __restrict__ vmat,   // (B*T, D)
    const int* __restrict__ spk)      // (B*T)
{
    const int row = blockIdx.x;            // (b*T+t)*L + l
    const int bt  = row >> 6;              // b*T + t
    const int b   = bt >> 5;               // /T
    const int t   = bt & 31;
    const int tid = threadIdx.x;

    __shared__ float toks[DD];
    __shared__ float p[TT];

    for (int d = tid; d < DD; d += 256) toks[d] = x[(size_t)row * DD + d];
    __syncthreads();

    // 32 groups of 8 threads, group u computes dot(tok, v[b,u])
    const int u = tid >> 3;
    const int lane8 = tid & 7;
    {
        const float* vrow = vmat + (size_t)(b * TT + u) * DD;
        float s = 0.f;
        for (int d = lane8; d < DD; d += 8) s += toks[d] * vrow[d];
        s += __shfl_down(s, 4, 8);
        s += __shfl_down(s, 2, 8);
        s += __shfl_down(s, 1, 8);
        if (lane8 == 0) {
            bool m = (u <= t) && (spk[b * TT + u] == spk[bt]);
            p[u] = m ? s : 0.f;
        }
    }
    __syncthreads();

    for (int d = tid; d < DD; d += 256) {
        float acc = toks[d];
#pragma unroll
        for (int u2 = 0; u2 < TT; ++u2)
            acc = fmaf(p[u2], kmat[(size_t)(b * TT + u2) * DD + d], acc);
        x[(size_t)row * DD + d] = acc;
    }
}

// ---------------------------------------------------------------------------
// MHA core per (n, h): softmax(q k^T / 8) v. L=64, DH=64.
// qkv layout: (8192, 2304) with q|k|v concatenated.
__global__ __launch_bounds__(256) void attn_kernel(
    const float* __restrict__ qkv, float* __restrict__ out)
{
    const int n = blockIdx.x;     // 0..127
    const int h = blockIdx.y;     // 0..11
    __shared__ float qs[64][65];
    __shared__ float ks[64][65];
    __shared__ float vs[64][65];
    const int tid = threadIdx.x;

    const float* basep = qkv + (size_t)n * 64 * 2304 + h * 64;
    for (int i = tid; i < 4096; i += 256) {
        int l = i >> 6, d = i & 63;
        const float* rowp = basep + (size_t)l * 2304;
        qs[l][d] = rowp[d];
        ks[l][d] = rowp[768 + d];
        vs[l][d] = rowp[1536 + d];
    }
    __syncthreads();

    const int qi = tid >> 2;      // 0..63 row
    const int cg = tid & 3;       // 4 threads per row, 16 cols each
    float sc[16];
#pragma unroll
    for (int j = 0; j < 16; ++j) {
        int c = cg * 16 + j;
        float s = 0.f;
#pragma unroll
        for (int d = 0; d < 64; ++d) s = fmaf(qs[qi][d], ks[c][d], s);
        sc[j] = s * 0.125f;
    }
    float m = sc[0];
#pragma unroll
    for (int j = 1; j < 16; ++j) m = fmaxf(m, sc[j]);
    m = fmaxf(m, __shfl_xor(m, 1, 4));
    m = fmaxf(m, __shfl_xor(m, 2, 4));
    float sum = 0.f;
#pragma unroll
    for (int j = 0; j < 16; ++j) { sc[j] = __expf(sc[j] - m); sum += sc[j]; }
    sum += __shfl_xor(sum, 1, 4);
    sum += __shfl_xor(sum, 2, 4);
    const float inv = 1.0f / sum;

    __syncthreads();              // done reading ks; reuse as prob matrix
#pragma unroll
    for (int j = 0; j < 16; ++j) ks[qi][cg * 16 + j] = sc[j] * inv;
    __syncthreads();

    float o[16] = {};
    for (int kk = 0; kk < 64; ++kk) {
        float pr = ks[qi][kk];
#pragma unroll
        for (int j = 0; j < 16; ++j) o[j] = fmaf(pr, vs[kk][cg * 16 + j], o[j]);
    }
    float* orow = out + (size_t)(n * 64 + qi) * DD + h * 64 + cg * 16;
#pragma unroll
    for (int j = 0; j < 16; ++j) orow[j] = o[j];
}

// ---------------------------------------------------------------------------
// x = LayerNorm(x + y) * g + b, row length 768, in place on x.
__global__ __launch_bounds__(256) void add_ln_kernel(
    float* __restrict__ x, const float* __restrict__ y,
    const float* __restrict__ g, const float* __restrict__ bb)
{
    const int row = blockIdx.x;
    const int tid = threadIdx.x;
    __shared__ float red[4];
    __shared__ float stat[2];
    const size_t base = (size_t)row * DD;

    float v0 = x[base + tid]       + y[base + tid];
    float v1 = x[base + tid + 256] + y[base + tid + 256];
    float v2 = x[base + tid + 512] + y[base + tid + 512];

    float s = v0 + v1 + v2;
#pragma unroll
    for (int off = 32; off > 0; off >>= 1) s += __shfl_down(s, off);
    if ((tid & 63) == 0) red[tid >> 6] = s;
    __syncthreads();
    if (tid == 0) stat[0] = (red[0] + red[1] + red[2] + red[3]) * (1.0f / (float)DD);
    __syncthreads();
    const float mu = stat[0];

    float d0 = v0 - mu, d1 = v1 - mu, d2 = v2 - mu;
    float q = d0 * d0 + d1 * d1 + d2 * d2;
    __syncthreads();   // red reusable
#pragma unroll
    for (int off = 32; off > 0; off >>= 1) q += __shfl_down(q, off);
    if ((tid & 63) == 0) red[tid >> 6] = q;
    __syncthreads();
    if (tid == 0) stat[1] = (red[0] + red[1] + red[2] + red[3]) * (1.0f / (float)DD);
    __syncthreads();
    const float rstd = rsqrtf(stat[1] + 1e-5f);

    x[base + tid]       = d0 * rstd * g[tid]       + bb[tid];
    x[base + tid + 256] = d1 * rstd * g[tid + 256] + bb[tid + 256];
    x[base + tid + 512] = d2 * rstd * g[tid + 512] + bb[tid + 512];
}

// ---------------------------------------------------------------------------
extern "C" void kernel_launch(void* const* d_in, const int* in_sizes, int n_in,
                              void* d_out, int out_size, void* d_ws, size_t ws_size,
                              hipStream_t stream) {
    (void)in_sizes; (void)n_in; (void)out_size; (void)ws_size;
    const float* te  = (const float*)d_in[0];
    const int*   spk = (const int*)  d_in[1];
    const float* Wq  = (const float*)d_in[2];
    const float* Wk  = (const float*)d_in[3];
    const float* Wv  = (const float*)d_in[4];
    const float* ipw = (const float*)d_in[5];
    const float* ipb = (const float*)d_in[6];
    const float* ow  = (const float*)d_in[7];
    const float* ob  = (const float*)d_in[8];
    const float* g1  = (const float*)d_in[9];
    const float* b1  = (const float*)d_in[10];
    const float* f1w = (const float*)d_in[11];
    const float* f1b = (const float*)d_in[12];
    const float* f2w = (const float*)d_in[13];
    const float* f2b = (const float*)d_in[14];
    const float* g2  = (const float*)d_in[15];
    const float* b2  = (const float*)d_in[16];

    float* X    = (float*)d_out;                       // activations (8192,768)
    float* U    = (float*)d_ws;                        // (8192,2304) scratch
    float* Abuf = U + (size_t)ROWS * 2304;             // (8192,768)
    float* edu  = Abuf + (size_t)ROWS * DD;            // (128,768)
    float* kb   = edu + (size_t)BTN * DD;
    float* vb   = kb  + (size_t)BTN * DD;

    // 1. edu mean
    edu_mean_kernel<<<(BTN * DD) / 256, 256, 0, stream>>>(te, edu);
    // 2. k, v projections (M=128)
    gemm_abt_kernel<<<dim3(DD / GBN, BTN / GBM), 256, 0, stream>>>(edu, Wk, nullptr, kb, BTN, DD, DD, 0);
    gemm_abt_kernel<<<dim3(DD / GBN, BTN / GBM), 256, 0, stream>>>(edu, Wv, nullptr, vb, BTN, DD, DD, 0);
    // 3. tok = TE @ Wq^T  -> X
    gemm_abt_kernel<<<dim3(DD / GBN, ROWS / GBM), 256, 0, stream>>>(te, Wq, nullptr, X, ROWS, DD, DD, 0);
    // 4. SAUTE context, in place on X
    saute_kernel<<<ROWS, 256, 0, stream>>>(X, kb, vb, spk);

    // 5. transformer layers
    for (int l = 0; l < NLAYERS; ++l) {
        const float* ipw_l = ipw + (size_t)l * 3 * DD * DD;
        const float* ipb_l = ipb + (size_t)l * 3 * DD;
        const float* ow_l  = ow  + (size_t)l * DD * DD;
        const float* ob_l  = ob  + (size_t)l * DD;
        const float* f1w_l = f1w + (size_t)l * DFF * DD;
        const float* f1b_l = f1b + (size_t)l * DFF;
        const float* f2w_l = f2w + (size_t)l * DD * DFF;
        const float* f2b_l = f2b + (size_t)l * DD;

        // qkv = X @ in_proj^T + b  -> U
        gemm_abt_kernel<<<dim3((3 * DD) / GBN, ROWS / GBM), 256, 0, stream>>>(
            X, ipw_l, ipb_l, U, ROWS, 3 * DD, DD, 0);
        // attention -> Abuf
        attn_kernel<<<dim3(BTN, NHEAD), 256, 0, stream>>>(U, Abuf);
        // out proj -> U (qkv dead now)
        gemm_abt_kernel<<<dim3(DD / GBN, ROWS / GBM), 256, 0, stream>>>(
            Abuf, ow_l, ob_l, U, ROWS, DD, DD, 0);
        // X = LN(X + U)
        add_ln_kernel<<<ROWS, 256, 0, stream>>>(X, U, g1 + (size_t)l * DD, b1 + (size_t)l * DD);
        // H = relu(X @ ff1^T + b) -> U
        gemm_abt_kernel<<<dim3(DFF / GBN, ROWS / GBM), 256, 0, stream>>>(
            X, f1w_l, f1b_l, U, ROWS, DFF, DD, 1);
        // P = H @ ff2^T + b -> Abuf
        gemm_abt_kernel<<<dim3(DD / GBN, ROWS / GBM), 256, 0, stream>>>(
            U, f2w_l, f2b_l, Abuf, ROWS, DD, DFF, 0);
        // X = LN(X + Abuf)
        add_ln_kernel<<<ROWS, 256, 0, stream>>>(X, Abuf, g2 + (size_t)l * DD, b2 + (size_t)l * DD);
    }
}

// Round 5
// 777.690 us; speedup vs baseline: 5.5882x; 5.5882x over previous
//
#include <hip/hip_runtime.h>
#include <hip/hip_bf16.h>

// Problem constants
#define BB 4
#define TT 32
#define LL 64
#define DD 768
#define NHEAD 12
#define DH 64
#define DFF 2048
#define NLAYERS 2
#define ROWS (BB*TT*LL)      // 8192
#define BTN  (BB*TT)         // 128

typedef __attribute__((ext_vector_type(8))) short bf16x8;
typedef __attribute__((ext_vector_type(4))) float f32x4;

// ---------------------------------------------------------------------------
// fp32 -> bf16 cast, 4 elements / thread. n must be divisible by 4.
__global__ __launch_bounds__(256) void cast_bf16_kernel(
    const float* __restrict__ in, __hip_bfloat16* __restrict__ out, int n4)
{
    int i = blockIdx.x * 256 + threadIdx.x;
    if (i >= n4) return;
    float4 v = reinterpret_cast<const float4*>(in)[i];
    __hip_bfloat16 h0 = __float2bfloat16(v.x);
    __hip_bfloat16 h1 = __float2bfloat16(v.y);
    __hip_bfloat16 h2 = __float2bfloat16(v.z);
    __hip_bfloat16 h3 = __float2bfloat16(v.w);
    ushort4 o;
    o.x = *reinterpret_cast<unsigned short*>(&h0);
    o.y = *reinterpret_cast<unsigned short*>(&h1);
    o.z = *reinterpret_cast<unsigned short*>(&h2);
    o.w = *reinterpret_cast<unsigned short*>(&h3);
    reinterpret_cast<ushort4*>(out)[i] = o;
}

// ---------------------------------------------------------------------------
// edu = mean over L of token_embeddings  : (B,T,D), fp32
__global__ __launch_bounds__(256) void edu_mean_kernel(
    const float* __restrict__ te, float* __restrict__ edu)
{
    int idx = blockIdx.x * 256 + threadIdx.x;       // bt*768 + d
    int bt = idx / DD;
    int d  = idx - bt * DD;
    const float* p = te + ((size_t)bt * LL) * DD + d;
    float s = 0.f;
#pragma unroll
    for (int l = 0; l < LL; ++l) s += p[(size_t)l * DD];
    edu[idx] = s * (1.0f / (float)LL);
}

// ---------------------------------------------------------------------------
// Small fp32 GEMM (tiny M=128 k/v projections): C[M,N] = A[M,K] @ B[N,K]^T
#define GBM 64
#define GBN 64
#define GBK 16
__global__ __launch_bounds__(256) void gemm_abt_kernel(
    const float* __restrict__ A, const float* __restrict__ B,
    float* __restrict__ C, int M, int N, int K)
{
    __shared__ float As[GBM][GBK + 1];
    __shared__ float Bs[GBN][GBK + 1];
    const int bm = blockIdx.y * GBM;
    const int bn = blockIdx.x * GBN;
    const int tid = threadIdx.x;
    const int tx = tid & 15;
    const int ty = tid >> 4;
    const int lr = tid >> 2;
    const int lc = (tid & 3) << 2;

    float acc[4][4] = {};

    for (int k0 = 0; k0 < K; k0 += GBK) {
        float4 va = *reinterpret_cast<const float4*>(A + (size_t)(bm + lr) * K + k0 + lc);
        float4 vb = *reinterpret_cast<const float4*>(B + (size_t)(bn + lr) * K + k0 + lc);
        As[lr][lc + 0] = va.x; As[lr][lc + 1] = va.y;
        As[lr][lc + 2] = va.z; As[lr][lc + 3] = va.w;
        Bs[lr][lc + 0] = vb.x; Bs[lr][lc + 1] = vb.y;
        Bs[lr][lc + 2] = vb.z; Bs[lr][lc + 3] = vb.w;
        __syncthreads();
#pragma unroll
        for (int kk = 0; kk < GBK; ++kk) {
            float a[4], b[4];
#pragma unroll
            for (int i = 0; i < 4; ++i) a[i] = As[ty * 4 + i][kk];
#pragma unroll
            for (int j = 0; j < 4; ++j) b[j] = Bs[tx * 4 + j][kk];
#pragma unroll
            for (int i = 0; i < 4; ++i)
#pragma unroll
                for (int j = 0; j < 4; ++j)
                    acc[i][j] = fmaf(a[i], b[j], acc[i][j]);
        }
        __syncthreads();
    }
#pragma unroll
    for (int i = 0; i < 4; ++i)
#pragma unroll
        for (int j = 0; j < 4; ++j)
            C[(size_t)(bm + ty * 4 + i) * N + bn + tx * 4 + j] = acc[i][j];
}

// ---------------------------------------------------------------------------
// bf16 MFMA GEMM, register-staged LDS (no global_load_lds):
// C[M,N] = A[M,K] @ B[N,K]^T (+bias)(+relu)
// BM=BN=128, BK=32, 256 threads (4 waves 2x2), acc 4x4 of 16x16x32 frags.
// M%128==0, N%128==0, K%32==0. A,B bf16; bias fp32; out bf16 or fp32.
template<int OUT_BF16, int RELU>
__global__ __launch_bounds__(256) void gemm_bf16_kernel(
    const __hip_bfloat16* __restrict__ A,
    const __hip_bfloat16* __restrict__ B,
    const float* __restrict__ bias,
    void* __restrict__ Cout,
    int M, int N, int K)
{
    __shared__ short lA[128 * 32];
    __shared__ short lB[128 * 32];
    const int tid  = threadIdx.x;
    const int lane = tid & 63;
    const int w    = tid >> 6;
    const int wr   = w >> 1, wc = w & 1;
    const int bm = blockIdx.y * 128;
    const int bn = blockIdx.x * 128;

    const int sr = tid >> 2;            // 0..63 staging row
    const int sc = (tid & 3) << 3;      // 0,8,16,24 (elements)

    const short* Ag = reinterpret_cast<const short*>(A);
    const short* Bg = reinterpret_cast<const short*>(B);

    f32x4 acc[4][4] = {};

    // prologue: load tile 0 into registers
    bf16x8 ra0 = *reinterpret_cast<const bf16x8*>(Ag + (size_t)(bm + sr) * K + sc);
    bf16x8 ra1 = *reinterpret_cast<const bf16x8*>(Ag + (size_t)(bm + 64 + sr) * K + sc);
    bf16x8 rb0 = *reinterpret_cast<const bf16x8*>(Bg + (size_t)(bn + sr) * K + sc);
    bf16x8 rb1 = *reinterpret_cast<const bf16x8*>(Bg + (size_t)(bn + 64 + sr) * K + sc);

    for (int k0 = 0; k0 < K; k0 += 32) {
        __syncthreads();   // previous iteration's LDS readers are done
        *reinterpret_cast<bf16x8*>(&lA[sr * 32 + sc])        = ra0;
        *reinterpret_cast<bf16x8*>(&lA[(64 + sr) * 32 + sc]) = ra1;
        *reinterpret_cast<bf16x8*>(&lB[sr * 32 + sc])        = rb0;
        *reinterpret_cast<bf16x8*>(&lB[(64 + sr) * 32 + sc]) = rb1;
        __syncthreads();   // tile visible to all waves

        // prefetch next tile into registers; latency hides under MFMA below
        if (k0 + 32 < K) {
            const int kn = k0 + 32;
            ra0 = *reinterpret_cast<const bf16x8*>(Ag + (size_t)(bm + sr) * K + kn + sc);
            ra1 = *reinterpret_cast<const bf16x8*>(Ag + (size_t)(bm + 64 + sr) * K + kn + sc);
            rb0 = *reinterpret_cast<const bf16x8*>(Bg + (size_t)(bn + sr) * K + kn + sc);
            rb1 = *reinterpret_cast<const bf16x8*>(Bg + (size_t)(bn + 64 + sr) * K + kn + sc);
        }

        bf16x8 af[4], bfr[4];
#pragma unroll
        for (int m = 0; m < 4; ++m)
            af[m] = *reinterpret_cast<const bf16x8*>(
                &lA[(wr * 64 + m * 16 + (lane & 15)) * 32 + (lane >> 4) * 8]);
#pragma unroll
        for (int n = 0; n < 4; ++n)
            bfr[n] = *reinterpret_cast<const bf16x8*>(
                &lB[(wc * 64 + n * 16 + (lane & 15)) * 32 + (lane >> 4) * 8]);
#pragma unroll
        for (int m = 0; m < 4; ++m)
#pragma unroll
            for (int n = 0; n < 4; ++n)
                acc[m][n] = __builtin_amdgcn_mfma_f32_16x16x32_bf16(
                    af[m], bfr[n], acc[m][n], 0, 0, 0);
    }

    const int crow = (lane >> 4) * 4;    // +reg j
    const int ccol = lane & 15;
#pragma unroll
    for (int n = 0; n < 4; ++n) {
        const int col = bn + wc * 64 + n * 16 + ccol;
        const float bv = bias ? bias[col] : 0.f;
#pragma unroll
        for (int m = 0; m < 4; ++m) {
            const int row0 = bm + wr * 64 + m * 16 + crow;
#pragma unroll
            for (int j = 0; j < 4; ++j) {
                float v = acc[m][n][j] + bv;
                if (RELU) v = fmaxf(v, 0.f);
                if (OUT_BF16)
                    reinterpret_cast<__hip_bfloat16*>(Cout)[(size_t)(row0 + j) * N + col] =
                        __float2bfloat16(v);
                else
                    reinterpret_cast<float*>(Cout)[(size_t)(row0 + j) * N + col] = v;
            }
        }
    }
}

// ---------------------------------------------------------------------------
// SAUTE context (in place on fp32 x), also emits bf16 copy:
//   x[row,:] += sum_u mask(b,t,u) * (v[b,u,:] . x[row,:]) * k[b,u,:]
__global__ __launch_bounds__(256) void saute_kernel(
    float* __restrict__ x, __hip_bfloat16* __restrict__ xb,
    const float* __restrict__ kmat, const float* __restrict__ vmat,
    const int* __restrict__ spk)
{
    const int row = blockIdx.x;
    const int bt  = row >> 6;
    const int b   = bt >> 5;
    const int t   = bt & 31;
    const int tid = threadIdx.x;

    __shared__ float toks[DD];
    __shared__ float p[TT];

    for (int d = tid; d < DD; d += 256) toks[d] = x[(size_t)row * DD + d];
    __syncthreads();

    const int u = tid >> 3;
    const int lane8 = tid & 7;
    {
        const float* vrow = vmat + (size_t)(b * TT + u) * DD;
        float s = 0.f;
        for (int d = lane8; d < DD; d += 8) s += toks[d] * vrow[d];
        s += __shfl_down(s, 4, 8);
        s += __shfl_down(s, 2, 8);
        s += __shfl_down(s, 1, 8);
        if (lane8 == 0) {
            bool m = (u <= t) && (spk[b * TT + u] == spk[bt]);
            p[u] = m ? s : 0.f;
        }
    }
    __syncthreads();

    for (int d = tid; d < DD; d += 256) {
        float acc = toks[d];
#pragma unroll
        for (int u2 = 0; u2 < TT; ++u2)
            acc = fmaf(p[u2], kmat[(size_t)(b * TT + u2) * DD + d], acc);
        x[(size_t)row * DD + d]  = acc;
        xb[(size_t)row * DD + d] = __float2bfloat16(acc);
    }
}

// ---------------------------------------------------------------------------
// MHA core per (n, h): softmax(q k^T / 8) v. bf16 in, bf16 out, fp32 math.
__global__ __launch_bounds__(256) void attn_kernel(
    const __hip_bfloat16* __restrict__ qkv, __hip_bfloat16* __restrict__ out)
{
    const int n = blockIdx.x;
    const int h = blockIdx.y;
    __shared__ float qs[64][65];
    __shared__ float ks[64][65];
    __shared__ float vs[64][65];
    const int tid = threadIdx.x;

    const __hip_bfloat16* basep = qkv + (size_t)n * 64 * 2304 + h * 64;
    for (int i = tid; i < 4096; i += 256) {
        int l = i >> 6, d = i & 63;
        const __hip_bfloat16* rowp = basep + (size_t)l * 2304;
        qs[l][d] = __bfloat162float(rowp[d]);
        ks[l][d] = __bfloat162float(rowp[768 + d]);
        vs[l][d] = __bfloat162float(rowp[1536 + d]);
    }
    __syncthreads();

    const int qi = tid >> 2;
    const int cg = tid & 3;
    float sc[16];
#pragma unroll
    for (int j = 0; j < 16; ++j) {
        int c = cg * 16 + j;
        float s = 0.f;
#pragma unroll
        for (int d = 0; d < 64; ++d) s = fmaf(qs[qi][d], ks[c][d], s);
        sc[j] = s * 0.125f;
    }
    float m = sc[0];
#pragma unroll
    for (int j = 1; j < 16; ++j) m = fmaxf(m, sc[j]);
    m = fmaxf(m, __shfl_xor(m, 1, 4));
    m = fmaxf(m, __shfl_xor(m, 2, 4));
    float sum = 0.f;
#pragma unroll
    for (int j = 0; j < 16; ++j) { sc[j] = __expf(sc[j] - m); sum += sc[j]; }
    sum += __shfl_xor(sum, 1, 4);
    sum += __shfl_xor(sum, 2, 4);
    const float inv = 1.0f / sum;

    __syncthreads();
#pragma unroll
    for (int j = 0; j < 16; ++j) ks[qi][cg * 16 + j] = sc[j] * inv;
    __syncthreads();

    float o[16] = {};
    for (int kk = 0; kk < 64; ++kk) {
        float pr = ks[qi][kk];
#pragma unroll
        for (int j = 0; j < 16; ++j) o[j] = fmaf(pr, vs[kk][cg * 16 + j], o[j]);
    }
    __hip_bfloat16* orow = out + (size_t)(n * 64 + qi) * DD + h * 64 + cg * 16;
#pragma unroll
    for (int j = 0; j < 16; ++j) orow[j] = __float2bfloat16(o[j]);
}

// ---------------------------------------------------------------------------
// x = LayerNorm(x + y) * g + b; x fp32 in place, y bf16; also emit bf16 copy.
__global__ __launch_bounds__(256) void add_ln_kernel(
    float* __restrict__ x, const __hip_bfloat16* __restrict__ y,
    const float* __restrict__ g, const float* __restrict__ bb,
    __hip_bfloat16* __restrict__ xb)
{
    const int row = blockIdx.x;
    const int tid = threadIdx.x;
    __shared__ float red[4];
    __shared__ float stat[2];
    const size_t base = (size_t)row * DD;

    float v0 = x[base + tid]       + __bfloat162float(y[base + tid]);
    float v1 = x[base + tid + 256] + __bfloat162float(y[base + tid + 256]);
    float v2 = x[base + tid + 512] + __bfloat162float(y[base + tid + 512]);

    float s = v0 + v1 + v2;
#pragma unroll
    for (int off = 32; off > 0; off >>= 1) s += __shfl_down(s, off);
    if ((tid & 63) == 0) red[tid >> 6] = s;
    __syncthreads();
    if (tid == 0) stat[0] = (red[0] + red[1] + red[2] + red[3]) * (1.0f / (float)DD);
    __syncthreads();
    const float mu = stat[0];

    float d0 = v0 - mu, d1 = v1 - mu, d2 = v2 - mu;
    float q = d0 * d0 + d1 * d1 + d2 * d2;
    __syncthreads();
#pragma unroll
    for (int off = 32; off > 0; off >>= 1) q += __shfl_down(q, off);
    if ((tid & 63) == 0) red[tid >> 6] = q;
    __syncthreads();
    if (tid == 0) stat[1] = (red[0] + red[1] + red[2] + red[3]) * (1.0f / (float)DD);
    __syncthreads();
    const float rstd = rsqrtf(stat[1] + 1e-5f);

    float o0 = d0 * rstd * g[tid]       + bb[tid];
    float o1 = d1 * rstd * g[tid + 256] + bb[tid + 256];
    float o2 = d2 * rstd * g[tid + 512] + bb[tid + 512];
    x[base + tid]        = o0;
    x[base + tid + 256]  = o1;
    x[base + tid + 512]  = o2;
    xb[base + tid]       = __float2bfloat16(o0);
    xb[base + tid + 256] = __float2bfloat16(o1);
    xb[base + tid + 512] = __float2bfloat16(o2);
}

// ---------------------------------------------------------------------------
extern "C" void kernel_launch(void* const* d_in, const int* in_sizes, int n_in,
                              void* d_out, int out_size, void* d_ws, size_t ws_size,
                              hipStream_t stream) {
    (void)in_sizes; (void)n_in; (void)out_size; (void)ws_size;
    const float* te  = (const float*)d_in[0];
    const int*   spk = (const int*)  d_in[1];
    const float* Wq  = (const float*)d_in[2];
    const float* Wk  = (const float*)d_in[3];
    const float* Wv  = (const float*)d_in[4];
    const float* ipw = (const float*)d_in[5];
    const float* ipb = (const float*)d_in[6];
    const float* ow  = (const float*)d_in[7];
    const float* ob  = (const float*)d_in[8];
    const float* g1  = (const float*)d_in[9];
    const float* b1  = (const float*)d_in[10];
    const float* f1w = (const float*)d_in[11];
    const float* f1b = (const float*)d_in[12];
    const float* f2w = (const float*)d_in[13];
    const float* f2b = (const float*)d_in[14];
    const float* g2  = (const float*)d_in[15];
    const float* b2  = (const float*)d_in[16];

    float* X = (float*)d_out;                          // residual stream (8192,768)

    // ws layout (bf16 region first, all byte offsets multiples of 16)
    __hip_bfloat16* wsb   = (__hip_bfloat16*)d_ws;
    __hip_bfloat16* Wq_b  = wsb;                               //   589,824
    __hip_bfloat16* ipw_b = Wq_b  + 589824;                    // 3,538,944
    __hip_bfloat16* ow_b  = ipw_b + 3538944;                   // 1,179,648
    __hip_bfloat16* f1w_b = ow_b  + 1179648;                   // 3,145,728
    __hip_bfloat16* f2w_b = f1w_b + 3145728;                   // 3,145,728
    __hip_bfloat16* Xb    = f2w_b + 3145728;                   // 6,291,456
    __hip_bfloat16* SCR   = Xb    + 6291456;                   // 18,874,368 (qkv / ffn-hidden)
    __hip_bfloat16* Ab    = SCR   + 18874368;                  // 6,291,456 (attn out; TE cast early)
    __hip_bfloat16* Yb    = Ab    + 6291456;                   // 6,291,456 (gemm out for residual)
    float* fws = (float*)(Yb + 6291456);
    float* edu = fws;                                          // 98,304
    float* kb  = edu + BTN * DD;
    float* vb  = kb  + BTN * DD;

    // 1. one-time casts: weights + token embeddings (TE cast lives in Ab, dead before attn)
    cast_bf16_kernel<<<(589824/4 + 255)/256, 256, 0, stream>>>(Wq, Wq_b, 589824/4);
    cast_bf16_kernel<<<(3538944/4 + 255)/256, 256, 0, stream>>>(ipw, ipw_b, 3538944/4);
    cast_bf16_kernel<<<(1179648/4 + 255)/256, 256, 0, stream>>>(ow, ow_b, 1179648/4);
    cast_bf16_kernel<<<(3145728/4 + 255)/256, 256, 0, stream>>>(f1w, f1w_b, 3145728/4);
    cast_bf16_kernel<<<(3145728/4 + 255)/256, 256, 0, stream>>>(f2w, f2w_b, 3145728/4);
    cast_bf16_kernel<<<(6291456/4 + 255)/256, 256, 0, stream>>>(te, Ab, 6291456/4);

    // 2. edu mean + tiny fp32 k/v projections
    edu_mean_kernel<<<(BTN * DD) / 256, 256, 0, stream>>>(te, edu);
    gemm_abt_kernel<<<dim3(DD/GBN, BTN/GBM), 256, 0, stream>>>(edu, Wk, kb, BTN, DD, DD);
    gemm_abt_kernel<<<dim3(DD/GBN, BTN/GBM), 256, 0, stream>>>(edu, Wv, vb, BTN, DD, DD);

    // 3. tok = TE @ Wq^T  (fp32 out -> X)
    gemm_bf16_kernel<0,0><<<dim3(DD/128, ROWS/128), 256, 0, stream>>>(
        Ab, Wq_b, nullptr, X, ROWS, DD, DD);

    // 4. SAUTE context, in place on X (+ bf16 copy)
    saute_kernel<<<ROWS, 256, 0, stream>>>(X, Xb, kb, vb, spk);

    // 5. transformer layers
    for (int l = 0; l < NLAYERS; ++l) {
        const __hip_bfloat16* ipw_l = ipw_b + (size_t)l * 3 * DD * DD;
        const __hip_bfloat16* ow_l  = ow_b  + (size_t)l * DD * DD;
        const __hip_bfloat16* f1w_l = f1w_b + (size_t)l * DFF * DD;
        const __hip_bfloat16* f2w_l = f2w_b + (size_t)l * DD * DFF;

        // qkv = Xb @ in_proj^T + b  -> SCR (bf16)
        gemm_bf16_kernel<1,0><<<dim3(3*DD/128, ROWS/128), 256, 0, stream>>>(
            Xb, ipw_l, ipb + (size_t)l * 3 * DD, SCR, ROWS, 3*DD, DD);
        // attention -> Ab (bf16)
        attn_kernel<<<dim3(BTN, NHEAD), 256, 0, stream>>>(SCR, Ab);
        // out proj -> Yb (bf16)
        gemm_bf16_kernel<1,0><<<dim3(DD/128, ROWS/128), 256, 0, stream>>>(
            Ab, ow_l, ob + (size_t)l * DD, Yb, ROWS, DD, DD);
        // X = LN(X + Yb)
        add_ln_kernel<<<ROWS, 256, 0, stream>>>(X, Yb, g1 + (size_t)l * DD, b1 + (size_t)l * DD, Xb);
        // H = relu(Xb @ ff1^T + b) -> SCR (bf16)
        gemm_bf16_kernel<1,1><<<dim3(DFF/128, ROWS/128), 256, 0, stream>>>(
            Xb, f1w_l, f1b + (size_t)l * DFF, SCR, ROWS, DFF, DD);
        // P = H @ ff2^T + b -> Yb (bf16), K=2048
        gemm_bf16_kernel<1,0><<<dim3(DD/128, ROWS/128), 256, 0, stream>>>(
            SCR, f2w_l, f2b + (size_t)l * DD, Yb, ROWS, DD, DFF);
        // X = LN(X + Yb)
        add_ln_kernel<<<ROWS, 256, 0, stream>>>(X, Yb, g2 + (size_t)l * DD, b2 + (size_t)l * DD, Xb);
    }
}

// Round 7
// 733.779 us; speedup vs baseline: 5.9227x; 1.0598x over previous
//
#include <hip/hip_runtime.h>
#include <hip/hip_bf16.h>

// Problem constants
#define BB 4
#define TT 32
#define LL 64
#define DD 768
#define NHEAD 12
#define DH 64
#define DFF 2048
#define NLAYERS 2
#define ROWS (BB*TT*LL)      // 8192
#define BTN  (BB*TT)         // 128

typedef __attribute__((ext_vector_type(8))) short bf16x8;
typedef __attribute__((ext_vector_type(4))) float f32x4;

// XOR swizzle for 128x32-short LDS tiles: row r (0..127), 16B chunk c (0..3).
// Spreads the 16 rows a lane-group reads across all 8 bank-slots (2-way max).
__device__ __forceinline__ int swz(int r, int c) {
    return r * 32 + ((c ^ ((r >> 1) & 3)) << 3);
}

__device__ __forceinline__ unsigned pack_bf16(float a, float b) {
    __hip_bfloat16 h0 = __float2bfloat16(a);
    __hip_bfloat16 h1 = __float2bfloat16(b);
    return (unsigned)*reinterpret_cast<unsigned short*>(&h0) |
           ((unsigned)*reinterpret_cast<unsigned short*>(&h1) << 16);
}

// ---------------------------------------------------------------------------
// fp32 -> bf16 cast, 4 elements / thread.
__global__ __launch_bounds__(256) void cast_bf16_kernel(
    const float* __restrict__ in, __hip_bfloat16* __restrict__ out, int n4)
{
    int i = blockIdx.x * 256 + threadIdx.x;
    if (i >= n4) return;
    float4 v = reinterpret_cast<const float4*>(in)[i];
    __hip_bfloat16 h0 = __float2bfloat16(v.x);
    __hip_bfloat16 h1 = __float2bfloat16(v.y);
    __hip_bfloat16 h2 = __float2bfloat16(v.z);
    __hip_bfloat16 h3 = __float2bfloat16(v.w);
    ushort4 o;
    o.x = *reinterpret_cast<unsigned short*>(&h0);
    o.y = *reinterpret_cast<unsigned short*>(&h1);
    o.z = *reinterpret_cast<unsigned short*>(&h2);
    o.w = *reinterpret_cast<unsigned short*>(&h3);
    reinterpret_cast<ushort4*>(out)[i] = o;
}

// ---------------------------------------------------------------------------
// Fused: teb = bf16(te), edu = mean over L of te. One read of te.
// grid = BTN*DD/256 = 384, thread idx = bt*768 + d.
__global__ __launch_bounds__(256) void te_prep_kernel(
    const float* __restrict__ te, __hip_bfloat16* __restrict__ teb,
    float* __restrict__ edu)
{
    int idx = blockIdx.x * 256 + threadIdx.x;
    int bt = idx / DD;
    int d  = idx - bt * DD;
    const float* p = te + ((size_t)bt * LL) * DD + d;
    __hip_bfloat16* q = teb + ((size_t)bt * LL) * DD + d;
    float s = 0.f;
#pragma unroll
    for (int l = 0; l < LL; ++l) {
        float v = p[(size_t)l * DD];
        s += v;
        q[(size_t)l * DD] = __float2bfloat16(v);
    }
    edu[idx] = s * (1.0f / (float)LL);
}

// ---------------------------------------------------------------------------
// Small fp32 GEMM (tiny M=128 k/v projections): C[M,N] = A[M,K] @ B[N,K]^T
#define GBM 64
#define GBN 64
#define GBK 16
__global__ __launch_bounds__(256) void gemm_abt_kernel(
    const float* __restrict__ A, const float* __restrict__ B,
    float* __restrict__ C, int M, int N, int K)
{
    __shared__ float As[GBM][GBK + 1];
    __shared__ float Bs[GBN][GBK + 1];
    const int bm = blockIdx.y * GBM;
    const int bn = blockIdx.x * GBN;
    const int tid = threadIdx.x;
    const int tx = tid & 15;
    const int ty = tid >> 4;
    const int lr = tid >> 2;
    const int lc = (tid & 3) << 2;

    float acc[4][4] = {};

    for (int k0 = 0; k0 < K; k0 += GBK) {
        float4 va = *reinterpret_cast<const float4*>(A + (size_t)(bm + lr) * K + k0 + lc);
        float4 vb = *reinterpret_cast<const float4*>(B + (size_t)(bn + lr) * K + k0 + lc);
        As[lr][lc + 0] = va.x; As[lr][lc + 1] = va.y;
        As[lr][lc + 2] = va.z; As[lr][lc + 3] = va.w;
        Bs[lr][lc + 0] = vb.x; Bs[lr][lc + 1] = vb.y;
        Bs[lr][lc + 2] = vb.z; Bs[lr][lc + 3] = vb.w;
        __syncthreads();
#pragma unroll
        for (int kk = 0; kk < GBK; ++kk) {
            float a[4], b[4];
#pragma unroll
            for (int i = 0; i < 4; ++i) a[i] = As[ty * 4 + i][kk];
#pragma unroll
            for (int j = 0; j < 4; ++j) b[j] = Bs[tx * 4 + j][kk];
#pragma unroll
            for (int i = 0; i < 4; ++i)
#pragma unroll
                for (int j = 0; j < 4; ++j)
                    acc[i][j] = fmaf(a[i], b[j], acc[i][j]);
        }
        __syncthreads();
    }
#pragma unroll
    for (int i = 0; i < 4; ++i)
#pragma unroll
        for (int j = 0; j < 4; ++j)
            C[(size_t)(bm + ty * 4 + i) * N + bn + tx * 4 + j] = acc[i][j];
}

// ---------------------------------------------------------------------------
// bf16 MFMA GEMM: reg-staged, double-buffered LDS (1 barrier / K-step),
// XOR-swizzled LDS (8-way read conflict -> 2-way).
// C[M,N] = A[M,K] @ B[N,K]^T (+bias)(+relu). BM=BN=128, BK=32, 256 thr.
template<int OUT_BF16, int RELU>
__global__ __launch_bounds__(256) void gemm_bf16_kernel(
    const __hip_bfloat16* __restrict__ A,
    const __hip_bfloat16* __restrict__ B,
    const float* __restrict__ bias,
    void* __restrict__ Cout,
    int M, int N, int K)
{
    __shared__ short lA[2][4096];
    __shared__ short lB[2][4096];
    const int tid  = threadIdx.x;
    const int lane = tid & 63;
    const int w    = tid >> 6;
    const int wr   = w >> 1, wc = w & 1;
    const int bm = blockIdx.y * 128;
    const int bn = blockIdx.x * 128;

    const int sr  = tid >> 2;           // 0..63 staging row
    const int cw  = tid & 3;            // 16B chunk
    const int sco = cw << 3;            // source col offset (elements)

    // swizzled LDS offsets (write side)
    const int wo0 = swz(sr, cw);
    const int wo1 = swz(sr + 64, cw);
    // swizzled LDS offsets (read side)
    int roA[4], roB[4];
#pragma unroll
    for (int m = 0; m < 4; ++m)
        roA[m] = swz(wr * 64 + m * 16 + (lane & 15), lane >> 4);
#pragma unroll
    for (int n = 0; n < 4; ++n)
        roB[n] = swz(wc * 64 + n * 16 + (lane & 15), lane >> 4);

    const short* Ag = reinterpret_cast<const short*>(A);
    const short* Bg = reinterpret_cast<const short*>(B);

    f32x4 acc[4][4] = {};

    // prologue: tile 0 -> regs -> LDS buf0
    bf16x8 ra0 = *reinterpret_cast<const bf16x8*>(Ag + (size_t)(bm + sr) * K + sco);
    bf16x8 ra1 = *reinterpret_cast<const bf16x8*>(Ag + (size_t)(bm + 64 + sr) * K + sco);
    bf16x8 rb0 = *reinterpret_cast<const bf16x8*>(Bg + (size_t)(bn + sr) * K + sco);
    bf16x8 rb1 = *reinterpret_cast<const bf16x8*>(Bg + (size_t)(bn + 64 + sr) * K + sco);
    *reinterpret_cast<bf16x8*>(&lA[0][wo0]) = ra0;
    *reinterpret_cast<bf16x8*>(&lA[0][wo1]) = ra1;
    *reinterpret_cast<bf16x8*>(&lB[0][wo0]) = rb0;
    *reinterpret_cast<bf16x8*>(&lB[0][wo1]) = rb1;
    __syncthreads();

    const int NT = K >> 5;
    int cur = 0;
    for (int t = 0; t < NT; ++t) {
        const bool nx = (t + 1 < NT);
        if (nx) {  // issue next-tile loads; latency hides under MFMA below
            const int kn = (t + 1) << 5;
            ra0 = *reinterpret_cast<const bf16x8*>(Ag + (size_t)(bm + sr) * K + kn + sco);
            ra1 = *reinterpret_cast<const bf16x8*>(Ag + (size_t)(bm + 64 + sr) * K + kn + sco);
            rb0 = *reinterpret_cast<const bf16x8*>(Bg + (size_t)(bn + sr) * K + kn + sco);
            rb1 = *reinterpret_cast<const bf16x8*>(Bg + (size_t)(bn + 64 + sr) * K + kn + sco);
        }

        bf16x8 af[4], bfr[4];
#pragma unroll
        for (int m = 0; m < 4; ++m)
            af[m] = *reinterpret_cast<const bf16x8*>(&lA[cur][roA[m]]);
#pragma unroll
        for (int n = 0; n < 4; ++n)
            bfr[n] = *reinterpret_cast<const bf16x8*>(&lB[cur][roB[n]]);
#pragma unroll
        for (int m = 0; m < 4; ++m)
#pragma unroll
            for (int n = 0; n < 4; ++n)
                acc[m][n] = __builtin_amdgcn_mfma_f32_16x16x32_bf16(
                    af[m], bfr[n], acc[m][n], 0, 0, 0);

        if (nx) {  // write next tile into the other buffer
            *reinterpret_cast<bf16x8*>(&lA[cur ^ 1][wo0]) = ra0;
            *reinterpret_cast<bf16x8*>(&lA[cur ^ 1][wo1]) = ra1;
            *reinterpret_cast<bf16x8*>(&lB[cur ^ 1][wo0]) = rb0;
            *reinterpret_cast<bf16x8*>(&lB[cur ^ 1][wo1]) = rb1;
        }
        __syncthreads();
        cur ^= 1;
    }

    const int crow = (lane >> 4) * 4;
    const int ccol = lane & 15;
#pragma unroll
    for (int n = 0; n < 4; ++n) {
        const int col = bn + wc * 64 + n * 16 + ccol;
        const float bv = bias ? bias[col] : 0.f;
#pragma unroll
        for (int m = 0; m < 4; ++m) {
            const int row0 = bm + wr * 64 + m * 16 + crow;
#pragma unroll
            for (int j = 0; j < 4; ++j) {
                float v = acc[m][n][j] + bv;
                if (RELU) v = fmaxf(v, 0.f);
                if (OUT_BF16)
                    reinterpret_cast<__hip_bfloat16*>(Cout)[(size_t)(row0 + j) * N + col] =
                        __float2bfloat16(v);
                else
                    reinterpret_cast<float*>(Cout)[(size_t)(row0 + j) * N + col] = v;
            }
        }
    }
}

// ---------------------------------------------------------------------------
// SAUTE part 1: P[row][u] = mask(b,t,u) * (tok[row,:] . v[b,u,:])
// 8 rows / block (grid ROWS/8 = 1024), v staged in LDS as packed bf16 pairs.
__global__ __launch_bounds__(256) void saute_p_kernel(
    const float* __restrict__ X, const float* __restrict__ vmat,
    const int* __restrict__ spk, float* __restrict__ P)
{
    __shared__ float toks[8 * DD];          // 24.6 KB
    __shared__ unsigned vls[32 * 392];      // 50.2 KB (bf16 pairs, pad 392)
    const int row0 = blockIdx.x * 8;
    const int bt = row0 >> 6, b = bt >> 5, t = bt & 31;
    const int tid = threadIdx.x;

    for (int i = tid; i < 8 * DD; i += 256)
        toks[i] = X[(size_t)row0 * DD + i];
    const float2* v2 = reinterpret_cast<const float2*>(vmat + (size_t)b * TT * DD);
    for (int i = tid; i < 32 * 384; i += 256) {
        int u = i / 384, j = i - u * 384;
        float2 f = v2[i];
        vls[u * 392 + j] = pack_bf16(f.x, f.y);
    }
    __syncthreads();

    const int u = tid >> 3, l8 = tid & 7;
    const int sb = spk[bt];
    const bool mk = (u <= t) && (spk[b * TT + u] == sb);
#pragma unroll
    for (int r = 0; r < 8; ++r) {
        float s = 0.f;
        const float* tr = &toks[r * DD];
        const unsigned* vr = &vls[u * 392];
        for (int j = l8; j < 384; j += 8) {
            unsigned pk = vr[j];
            s = fmaf(tr[2 * j],     __uint_as_float(pk << 16),          s);
            s = fmaf(tr[2 * j + 1], __uint_as_float(pk & 0xffff0000u), s);
        }
        s += __shfl_down(s, 4, 8);
        s += __shfl_down(s, 2, 8);
        s += __shfl_down(s, 1, 8);
        if (l8 == 0) P[(size_t)(row0 + r) * 32 + u] = mk ? s : 0.f;
    }
}

// ---------------------------------------------------------------------------
// SAUTE part 2: ctx[row,:] = tok[row,:] + sum_u P[row][u] * k[b,u,:]
// In place on X, also emits bf16 copy. 8 rows / block, k staged bf16 in LDS.
__global__ __launch_bounds__(256) void saute_ctx_kernel(
    float* __restrict__ X, __hip_bfloat16* __restrict__ Xb,
    const float* __restrict__ kmat, const float* __restrict__ P)
{
    __shared__ unsigned kls[32 * 384];      // 49.2 KB
    __shared__ float pls[8 * 32];
    const int row0 = blockIdx.x * 8;
    const int bt = row0 >> 6, b = bt >> 5;
    const int tid = threadIdx.x;

    const float2* k2 = reinterpret_cast<const float2*>(kmat + (size_t)b * TT * DD);
    for (int i = tid; i < 32 * 384; i += 256) {
        float2 f = k2[i];
        kls[i] = pack_bf16(f.x, f.y);
    }
    pls[tid] = P[(size_t)row0 * 32 + tid];   // 256 values exactly
    __syncthreads();

    float acc[3][8];
#pragma unroll
    for (int c = 0; c < 3; ++c)
#pragma unroll
        for (int r = 0; r < 8; ++r)
            acc[c][r] = X[(size_t)(row0 + r) * DD + tid + 256 * c];

    const int par = tid & 1;
    for (int u = 0; u < 32; ++u) {
        float pv[8];
#pragma unroll
        for (int r = 0; r < 8; ++r) pv[r] = pls[r * 32 + u];
#pragma unroll
        for (int c = 0; c < 3; ++c) {
            unsigned pk = kls[u * 384 + ((tid + 256 * c) >> 1)];
            float kv = par ? __uint_as_float(pk & 0xffff0000u)
                           : __uint_as_float(pk << 16);
#pragma unroll
            for (int r = 0; r < 8; ++r)
                acc[c][r] = fmaf(pv[r], kv, acc[c][r]);
        }
    }
#pragma unroll
    for (int c = 0; c < 3; ++c)
#pragma unroll
        for (int r = 0; r < 8; ++r) {
            size_t o = (size_t)(row0 + r) * DD + tid + 256 * c;
            X[o]  = acc[c][r];
            Xb[o] = __float2bfloat16(acc[c][r]);
        }
}

// ---------------------------------------------------------------------------
// MHA core per (n, h): softmax(q k^T / 8) v. bf16 in, bf16 out, fp32 math.
__global__ __launch_bounds__(256) void attn_kernel(
    const __hip_bfloat16* __restrict__ qkv, __hip_bfloat16* __restrict__ out)
{
    const int n = blockIdx.x;
    const int h = blockIdx.y;
    __shared__ float qs[64][65];
    __shared__ float ks[64][65];
    __shared__ float vs[64][65];
    const int tid = threadIdx.x;

    const __hip_bfloat16* basep = qkv + (size_t)n * 64 * 2304 + h * 64;
    for (int i = tid; i < 4096; i += 256) {
        int l = i >> 6, d = i & 63;
        const __hip_bfloat16* rowp = basep + (size_t)l * 2304;
        qs[l][d] = __bfloat162float(rowp[d]);
        ks[l][d] = __bfloat162float(rowp[768 + d]);
        vs[l][d] = __bfloat162float(rowp[1536 + d]);
    }
    __syncthreads();

    const int qi = tid >> 2;
    const int cg = tid & 3;
    float sc[16];
#pragma unroll
    for (int j = 0; j < 16; ++j) {
        int c = cg * 16 + j;
        float s = 0.f;
#pragma unroll
        for (int d = 0; d < 64; ++d) s = fmaf(qs[qi][d], ks[c][d], s);
        sc[j] = s * 0.125f;
    }
    float m = sc[0];
#pragma unroll
    for (int j = 1; j < 16; ++j) m = fmaxf(m, sc[j]);
    m = fmaxf(m, __shfl_xor(m, 1, 4));
    m = fmaxf(m, __shfl_xor(m, 2, 4));
    float sum = 0.f;
#pragma unroll
    for (int j = 0; j < 16; ++j) { sc[j] = __expf(sc[j] - m); sum += sc[j]; }
    sum += __shfl_xor(sum, 1, 4);
    sum += __shfl_xor(sum, 2, 4);
    const float inv = 1.0f / sum;

    __syncthreads();
#pragma unroll
    for (int j = 0; j < 16; ++j) ks[qi][cg * 16 + j] = sc[j] * inv;
    __syncthreads();

    float o[16] = {};
    for (int kk = 0; kk < 64; ++kk) {
        float pr = ks[qi][kk];
#pragma unroll
        for (int j = 0; j < 16; ++j) o[j] = fmaf(pr, vs[kk][cg * 16 + j], o[j]);
    }
    __hip_bfloat16* orow = out + (size_t)(n * 64 + qi) * DD + h * 64 + cg * 16;
#pragma unroll
    for (int j = 0; j < 16; ++j) orow[j] = __float2bfloat16(o[j]);
}

// ---------------------------------------------------------------------------
// x = LayerNorm(x + y) * g + b; x fp32 in place, y bf16; also emit bf16 copy.
__global__ __launch_bounds__(256) void add_ln_kernel(
    float* __restrict__ x, const __hip_bfloat16* __restrict__ y,
    const float* __restrict__ g, const float* __restrict__ bb,
    __hip_bfloat16* __restrict__ xb)
{
    const int row = blockIdx.x;
    const int tid = threadIdx.x;
    __shared__ float red[4];
    __shared__ float stat[2];
    const size_t base = (size_t)row * DD;

    float v0 = x[base + tid]       + __bfloat162float(y[base + tid]);
    float v1 = x[base + tid + 256] + __bfloat162float(y[base + tid + 256]);
    float v2 = x[base + tid + 512] + __bfloat162float(y[base + tid + 512]);

    float s = v0 + v1 + v2;
#pragma unroll
    for (int off = 32; off > 0; off >>= 1) s += __shfl_down(s, off);
    if ((tid & 63) == 0) red[tid >> 6] = s;
    __syncthreads();
    if (tid == 0) stat[0] = (red[0] + red[1] + red[2] + red[3]) * (1.0f / (float)DD);
    __syncthreads();
    const float mu = stat[0];

    float d0 = v0 - mu, d1 = v1 - mu, d2 = v2 - mu;
    float q = d0 * d0 + d1 * d1 + d2 * d2;
    __syncthreads();
#pragma unroll
    for (int off = 32; off > 0; off >>= 1) q += __shfl_down(q, off);
    if ((tid & 63) == 0) red[tid >> 6] = q;
    __syncthreads();
    if (tid == 0) stat[1] = (red[0] + red[1] + red[2] + red[3]) * (1.0f / (float)DD);
    __syncthreads();
    const float rstd = rsqrtf(stat[1] + 1e-5f);

    float o0 = d0 * rstd * g[tid]       + bb[tid];
    float o1 = d1 * rstd * g[tid + 256] + bb[tid + 256];
    float o2 = d2 * rstd * g[tid + 512] + bb[tid + 512];
    x[base + tid]        = o0;
    x[base + tid + 256]  = o1;
    x[base + tid + 512]  = o2;
    xb[base + tid]       = __float2bfloat16(o0);
    xb[base + tid + 256] = __float2bfloat16(o1);
    xb[base + tid + 512] = __float2bfloat16(o2);
}

// ---------------------------------------------------------------------------
extern "C" void kernel_launch(void* const* d_in, const int* in_sizes, int n_in,
                              void* d_out, int out_size, void* d_ws, size_t ws_size,
                              hipStream_t stream) {
    (void)in_sizes; (void)n_in; (void)out_size; (void)ws_size;
    const float* te  = (const float*)d_in[0];
    const int*   spk = (const int*)  d_in[1];
    const float* Wq  = (const float*)d_in[2];
    const float* Wk  = (const float*)d_in[3];
    const float* Wv  = (const float*)d_in[4];
    const float* ipw = (const float*)d_in[5];
    const float* ipb = (const float*)d_in[6];
    const float* ow  = (const float*)d_in[7];
    const float* ob  = (const float*)d_in[8];
    const float* g1  = (const float*)d_in[9];
    const float* b1  = (const float*)d_in[10];
    const float* f1w = (const float*)d_in[11];
    const float* f1b = (const float*)d_in[12];
    const float* f2w = (const float*)d_in[13];
    const float* f2b = (const float*)d_in[14];
    const float* g2  = (const float*)d_in[15];
    const float* b2  = (const float*)d_in[16];

    float* X = (float*)d_out;                          // residual stream (8192,768)

    // ws layout (bf16 region first, all byte offsets multiples of 16)
    __hip_bfloat16* wsb   = (__hip_bfloat16*)d_ws;
    __hip_bfloat16* Wq_b  = wsb;                               //   589,824
    __hip_bfloat16* ipw_b = Wq_b  + 589824;                    // 3,538,944
    __hip_bfloat16* ow_b  = ipw_b + 3538944;                   // 1,179,648
    __hip_bfloat16* f1w_b = ow_b  + 1179648;                   // 3,145,728
    __hip_bfloat16* f2w_b = f1w_b + 3145728;                   // 3,145,728
    __hip_bfloat16* Xb    = f2w_b + 3145728;                   // 6,291,456
    __hip_bfloat16* SCR   = Xb    + 6291456;                   // 18,874,368 (qkv / ffn-hidden)
    __hip_bfloat16* Ab    = SCR   + 18874368;                  // 6,291,456 (attn out; TE cast early)
    __hip_bfloat16* Yb    = Ab    + 6291456;                   // 6,291,456 (gemm out for residual)
    float* fws = (float*)(Yb + 6291456);
    float* edu = fws;                                          // 98,304
    float* kb  = edu + BTN * DD;                               // 98,304
    float* vb  = kb  + BTN * DD;                               // 98,304
    float* Pbuf= vb  + BTN * DD;                               // 262,144

    // 1. te prep (bf16 cast into Ab + edu mean) and weight casts
    te_prep_kernel<<<(BTN * DD) / 256, 256, 0, stream>>>(te, Ab, edu);
    cast_bf16_kernel<<<(589824/4 + 255)/256, 256, 0, stream>>>(Wq, Wq_b, 589824/4);
    cast_bf16_kernel<<<(3538944/4 + 255)/256, 256, 0, stream>>>(ipw, ipw_b, 3538944/4);
    cast_bf16_kernel<<<(1179648/4 + 255)/256, 256, 0, stream>>>(ow, ow_b, 1179648/4);
    cast_bf16_kernel<<<(3145728/4 + 255)/256, 256, 0, stream>>>(f1w, f1w_b, 3145728/4);
    cast_bf16_kernel<<<(3145728/4 + 255)/256, 256, 0, stream>>>(f2w, f2w_b, 3145728/4);

    // 2. tiny fp32 k/v projections
    gemm_abt_kernel<<<dim3(DD/GBN, BTN/GBM), 256, 0, stream>>>(edu, Wk, kb, BTN, DD, DD);
    gemm_abt_kernel<<<dim3(DD/GBN, BTN/GBM), 256, 0, stream>>>(edu, Wv, vb, BTN, DD, DD);

    // 3. tok = TE @ Wq^T  (fp32 out -> X)
    gemm_bf16_kernel<0,0><<<dim3(DD/128, ROWS/128), 256, 0, stream>>>(
        Ab, Wq_b, nullptr, X, ROWS, DD, DD);

    // 4. SAUTE: P = masked tok.v, then ctx = tok + P @ k (in place on X, + bf16)
    saute_p_kernel<<<ROWS/8, 256, 0, stream>>>(X, vb, spk, Pbuf);
    saute_ctx_kernel<<<ROWS/8, 256, 0, stream>>>(X, Xb, kb, Pbuf);

    // 5. transformer layers
    for (int l = 0; l < NLAYERS; ++l) {
        const __hip_bfloat16* ipw_l = ipw_b + (size_t)l * 3 * DD * DD;
        const __hip_bfloat16* ow_l  = ow_b  + (size_t)l * DD * DD;
        const __hip_bfloat16* f1w_l = f1w_b + (size_t)l * DFF * DD;
        const __hip_bfloat16* f2w_l = f2w_b + (size_t)l * DD * DFF;

        // qkv = Xb @ in_proj^T + b  -> SCR (bf16)
        gemm_bf16_kernel<1,0><<<dim3(3*DD/128, ROWS/128), 256, 0, stream>>>(
            Xb, ipw_l, ipb + (size_t)l * 3 * DD, SCR, ROWS, 3*DD, DD);
        // attention -> Ab (bf16)
        attn_kernel<<<dim3(BTN, NHEAD), 256, 0, stream>>>(SCR, Ab);
        // out proj -> Yb (bf16)
        gemm_bf16_kernel<1,0><<<dim3(DD/128, ROWS/128), 256, 0, stream>>>(
            Ab, ow_l, ob + (size_t)l * DD, Yb, ROWS, DD, DD);
        // X = LN(X + Yb)
        add_ln_kernel<<<ROWS, 256, 0, stream>>>(X, Yb, g1 + (size_t)l * DD, b1 + (size_t)l * DD, Xb);
        // H = relu(Xb @ ff1^T + b) -> SCR (bf16)
        gemm_bf16_kernel<1,1><<<dim3(DFF/128, ROWS/128), 256, 0, stream>>>(
            Xb, f1w_l, f1b + (size_t)l * DFF, SCR, ROWS, DFF, DD);
        // P = H @ ff2^T + b -> Yb (bf16), K=2048
        gemm_bf16_kernel<1,0><<<dim3(DD/128, ROWS/128), 256, 0, stream>>>(
            SCR, f2w_l, f2b + (size_t)l * DD, Yb, ROWS, DD, DFF);
        // X = LN(X + Yb)
        add_ln_kernel<<<ROWS, 256, 0, stream>>>(X, Yb, g2 + (size_t)l * DD, b2 + (size_t)l * DD, Xb);
    }
}

// Round 8
// 613.561 us; speedup vs baseline: 7.0831x; 1.1959x over previous
//
#include <hip/hip_runtime.h>
#include <hip/hip_bf16.h>

// Problem constants
#define BB 4
#define TT 32
#define LL 64
#define DD 768
#define NHEAD 12
#define DH 64
#define DFF 2048
#define NLAYERS 2
#define ROWS (BB*TT*LL)      // 8192
#define BTN  (BB*TT)         // 128

typedef __attribute__((ext_vector_type(8))) short bf16x8;
typedef __attribute__((ext_vector_type(4))) float f32x4;

// XOR swizzle for 128x32-short LDS tiles: row r (0..127), 16B chunk c (0..3).
__device__ __forceinline__ int swz(int r, int c) {
    return r * 32 + ((c ^ ((r >> 1) & 3)) << 3);
}

__device__ __forceinline__ unsigned pack_bf16(float a, float b) {
    __hip_bfloat16 h0 = __float2bfloat16(a);
    __hip_bfloat16 h1 = __float2bfloat16(b);
    return (unsigned)*reinterpret_cast<unsigned short*>(&h0) |
           ((unsigned)*reinterpret_cast<unsigned short*>(&h1) << 16);
}

__device__ __forceinline__ short bf16s(float a) {
    __hip_bfloat16 h = __float2bfloat16(a);
    return *reinterpret_cast<short*>(&h);
}

// ---------------------------------------------------------------------------
// fp32 -> bf16 cast, 4 elements / thread.
__global__ __launch_bounds__(256) void cast_bf16_kernel(
    const float* __restrict__ in, __hip_bfloat16* __restrict__ out, int n4)
{
    int i = blockIdx.x * 256 + threadIdx.x;
    if (i >= n4) return;
    float4 v = reinterpret_cast<const float4*>(in)[i];
    __hip_bfloat16 h0 = __float2bfloat16(v.x);
    __hip_bfloat16 h1 = __float2bfloat16(v.y);
    __hip_bfloat16 h2 = __float2bfloat16(v.z);
    __hip_bfloat16 h3 = __float2bfloat16(v.w);
    ushort4 o;
    o.x = *reinterpret_cast<unsigned short*>(&h0);
    o.y = *reinterpret_cast<unsigned short*>(&h1);
    o.z = *reinterpret_cast<unsigned short*>(&h2);
    o.w = *reinterpret_cast<unsigned short*>(&h3);
    reinterpret_cast<ushort4*>(out)[i] = o;
}

// ---------------------------------------------------------------------------
// Fused: teb = bf16(te), edu = mean over L of te. One read of te.
__global__ __launch_bounds__(256) void te_prep_kernel(
    const float* __restrict__ te, __hip_bfloat16* __restrict__ teb,
    float* __restrict__ edu)
{
    int idx = blockIdx.x * 256 + threadIdx.x;
    int bt = idx / DD;
    int d  = idx - bt * DD;
    const float* p = te + ((size_t)bt * LL) * DD + d;
    __hip_bfloat16* q = teb + ((size_t)bt * LL) * DD + d;
    float s = 0.f;
#pragma unroll
    for (int l = 0; l < LL; ++l) {
        float v = p[(size_t)l * DD];
        s += v;
        q[(size_t)l * DD] = __float2bfloat16(v);
    }
    edu[idx] = s * (1.0f / (float)LL);
}

// ---------------------------------------------------------------------------
// Small fp32 GEMM (tiny M=128 k/v projections): C[M,N] = A[M,K] @ B[N,K]^T
#define GBM 64
#define GBN 64
#define GBK 16
__global__ __launch_bounds__(256) void gemm_abt_kernel(
    const float* __restrict__ A, const float* __restrict__ B,
    float* __restrict__ C, int M, int N, int K)
{
    __shared__ float As[GBM][GBK + 1];
    __shared__ float Bs[GBN][GBK + 1];
    const int bm = blockIdx.y * GBM;
    const int bn = blockIdx.x * GBN;
    const int tid = threadIdx.x;
    const int tx = tid & 15;
    const int ty = tid >> 4;
    const int lr = tid >> 2;
    const int lc = (tid & 3) << 2;

    float acc[4][4] = {};

    for (int k0 = 0; k0 < K; k0 += GBK) {
        float4 va = *reinterpret_cast<const float4*>(A + (size_t)(bm + lr) * K + k0 + lc);
        float4 vb = *reinterpret_cast<const float4*>(B + (size_t)(bn + lr) * K + k0 + lc);
        As[lr][lc + 0] = va.x; As[lr][lc + 1] = va.y;
        As[lr][lc + 2] = va.z; As[lr][lc + 3] = va.w;
        Bs[lr][lc + 0] = vb.x; Bs[lr][lc + 1] = vb.y;
        Bs[lr][lc + 2] = vb.z; Bs[lr][lc + 3] = vb.w;
        __syncthreads();
#pragma unroll
        for (int kk = 0; kk < GBK; ++kk) {
            float a[4], b[4];
#pragma unroll
            for (int i = 0; i < 4; ++i) a[i] = As[ty * 4 + i][kk];
#pragma unroll
            for (int j = 0; j < 4; ++j) b[j] = Bs[tx * 4 + j][kk];
#pragma unroll
            for (int i = 0; i < 4; ++i)
#pragma unroll
                for (int j = 0; j < 4; ++j)
                    acc[i][j] = fmaf(a[i], b[j], acc[i][j]);
        }
        __syncthreads();
    }
#pragma unroll
    for (int i = 0; i < 4; ++i)
#pragma unroll
        for (int j = 0; j < 4; ++j)
            C[(size_t)(bm + ty * 4 + i) * N + bn + tx * 4 + j] = acc[i][j];
}

// ---------------------------------------------------------------------------
// bf16 MFMA GEMM: reg-staged, double-buffered LDS, XOR-swizzled.
// C[M,N] = A[M,K] @ B[N,K]^T (+bias)(+relu). BM=BN=128, BK=32, 256 thr.
// QKV mode: cols < 1536 -> Cout with leading dim ldC (=1536); cols >= 1536
// (the V third) are stored TRANSPOSED per head into Vout[n][h][d][l].
template<int OUT_BF16, int RELU, int QKV>
__global__ __launch_bounds__(256) void gemm_bf16_kernel(
    const __hip_bfloat16* __restrict__ A,
    const __hip_bfloat16* __restrict__ B,
    const float* __restrict__ bias,
    void* __restrict__ Cout,
    __hip_bfloat16* __restrict__ Vout,
    int M, int N, int K, int ldC)
{
    __shared__ short lA[2][4096];
    __shared__ short lB[2][4096];
    const int tid  = threadIdx.x;
    const int lane = tid & 63;
    const int w    = tid >> 6;
    const int wr   = w >> 1, wc = w & 1;
    const int bm = blockIdx.y * 128;
    const int bn = blockIdx.x * 128;

    const int sr  = tid >> 2;
    const int cw  = tid & 3;
    const int sco = cw << 3;

    const int wo0 = swz(sr, cw);
    const int wo1 = swz(sr + 64, cw);
    int roA[4], roB[4];
#pragma unroll
    for (int m = 0; m < 4; ++m)
        roA[m] = swz(wr * 64 + m * 16 + (lane & 15), lane >> 4);
#pragma unroll
    for (int n = 0; n < 4; ++n)
        roB[n] = swz(wc * 64 + n * 16 + (lane & 15), lane >> 4);

    const short* Ag = reinterpret_cast<const short*>(A);
    const short* Bg = reinterpret_cast<const short*>(B);

    f32x4 acc[4][4] = {};

    bf16x8 ra0 = *reinterpret_cast<const bf16x8*>(Ag + (size_t)(bm + sr) * K + sco);
    bf16x8 ra1 = *reinterpret_cast<const bf16x8*>(Ag + (size_t)(bm + 64 + sr) * K + sco);
    bf16x8 rb0 = *reinterpret_cast<const bf16x8*>(Bg + (size_t)(bn + sr) * K + sco);
    bf16x8 rb1 = *reinterpret_cast<const bf16x8*>(Bg + (size_t)(bn + 64 + sr) * K + sco);
    *reinterpret_cast<bf16x8*>(&lA[0][wo0]) = ra0;
    *reinterpret_cast<bf16x8*>(&lA[0][wo1]) = ra1;
    *reinterpret_cast<bf16x8*>(&lB[0][wo0]) = rb0;
    *reinterpret_cast<bf16x8*>(&lB[0][wo1]) = rb1;
    __syncthreads();

    const int NT = K >> 5;
    int cur = 0;
    for (int t = 0; t < NT; ++t) {
        const bool nx = (t + 1 < NT);
        if (nx) {
            const int kn = (t + 1) << 5;
            ra0 = *reinterpret_cast<const bf16x8*>(Ag + (size_t)(bm + sr) * K + kn + sco);
            ra1 = *reinterpret_cast<const bf16x8*>(Ag + (size_t)(bm + 64 + sr) * K + kn + sco);
            rb0 = *reinterpret_cast<const bf16x8*>(Bg + (size_t)(bn + sr) * K + kn + sco);
            rb1 = *reinterpret_cast<const bf16x8*>(Bg + (size_t)(bn + 64 + sr) * K + kn + sco);
        }

        bf16x8 af[4], bfr[4];
#pragma unroll
        for (int m = 0; m < 4; ++m)
            af[m] = *reinterpret_cast<const bf16x8*>(&lA[cur][roA[m]]);
#pragma unroll
        for (int n = 0; n < 4; ++n)
            bfr[n] = *reinterpret_cast<const bf16x8*>(&lB[cur][roB[n]]);
#pragma unroll
        for (int m = 0; m < 4; ++m)
#pragma unroll
            for (int n = 0; n < 4; ++n)
                acc[m][n] = __builtin_amdgcn_mfma_f32_16x16x32_bf16(
                    af[m], bfr[n], acc[m][n], 0, 0, 0);

        if (nx) {
            *reinterpret_cast<bf16x8*>(&lA[cur ^ 1][wo0]) = ra0;
            *reinterpret_cast<bf16x8*>(&lA[cur ^ 1][wo1]) = ra1;
            *reinterpret_cast<bf16x8*>(&lB[cur ^ 1][wo0]) = rb0;
            *reinterpret_cast<bf16x8*>(&lB[cur ^ 1][wo1]) = rb1;
        }
        __syncthreads();
        cur ^= 1;
    }

    const int crow = (lane >> 4) * 4;
    const int ccol = lane & 15;
#pragma unroll
    for (int n = 0; n < 4; ++n) {
        const int col = bn + wc * 64 + n * 16 + ccol;
        const float bv = bias ? bias[col] : 0.f;
        if (QKV && col >= 1536) {
            const int hh = (col - 1536) >> 6;
            const int d  = (col - 1536) & 63;
#pragma unroll
            for (int m = 0; m < 4; ++m) {
                const int row0 = bm + wr * 64 + m * 16 + crow;
#pragma unroll
                for (int j = 0; j < 4; ++j) {
                    const int row = row0 + j;
                    const int ni = row >> 6, ll = row & 63;
                    Vout[(((size_t)ni * NHEAD + hh) << 12) + (d << 6) + ll] =
                        __float2bfloat16(acc[m][n][j] + bv);
                }
            }
        } else {
#pragma unroll
            for (int m = 0; m < 4; ++m) {
                const int row0 = bm + wr * 64 + m * 16 + crow;
#pragma unroll
                for (int j = 0; j < 4; ++j) {
                    float v = acc[m][n][j] + bv;
                    if (RELU) v = fmaxf(v, 0.f);
                    if (OUT_BF16)
                        reinterpret_cast<__hip_bfloat16*>(Cout)[(size_t)(row0 + j) * ldC + col] =
                            __float2bfloat16(v);
                    else
                        reinterpret_cast<float*>(Cout)[(size_t)(row0 + j) * ldC + col] = v;
                }
            }
        }
    }
}

// ---------------------------------------------------------------------------
// MFMA attention: one wave per (n,h). qk: (8192,1536) bf16 Q|K rows;
// vt: (128,12,64,64) bf16 V^T; out: (8192,768) bf16.
__global__ __launch_bounds__(64) void attn_mfma_kernel(
    const __hip_bfloat16* __restrict__ qk,
    const __hip_bfloat16* __restrict__ vt,
    __hip_bfloat16* __restrict__ out)
{
    const int n = blockIdx.x, h = blockIdx.y;
    const int lane = threadIdx.x;
    const int lo = lane & 15, hi = lane >> 4;
    __shared__ short pl[64 * 72];      // P, stride 72 shorts (144 B, 16B-aligned)

    const short* qg = reinterpret_cast<const short*>(qk) + (size_t)(n * 64) * 1536 + h * 64;

    // S = Q @ K^T  (scaled)
    f32x4 acc[4][4] = {};
#pragma unroll
    for (int ks = 0; ks < 2; ++ks) {
        const int kc = ks * 32 + hi * 8;
        bf16x8 af[4], bk[4];
#pragma unroll
        for (int m = 0; m < 4; ++m)
            af[m] = *reinterpret_cast<const bf16x8*>(qg + (size_t)(m * 16 + lo) * 1536 + kc);
#pragma unroll
        for (int nn = 0; nn < 4; ++nn)
            bk[nn] = *reinterpret_cast<const bf16x8*>(qg + 768 + (size_t)(nn * 16 + lo) * 1536 + kc);
#pragma unroll
        for (int m = 0; m < 4; ++m)
#pragma unroll
            for (int nn = 0; nn < 4; ++nn)
                acc[m][nn] = __builtin_amdgcn_mfma_f32_16x16x32_bf16(
                    af[m], bk[nn], acc[m][nn], 0, 0, 0);
    }

    // row softmax (row r = m*16 + hi*4 + j; cols c = nn*16 + lo)
#pragma unroll
    for (int m = 0; m < 4; ++m) {
#pragma unroll
        for (int j = 0; j < 4; ++j) {
            float s0 = acc[m][0][j] * 0.125f;
            float s1 = acc[m][1][j] * 0.125f;
            float s2 = acc[m][2][j] * 0.125f;
            float s3 = acc[m][3][j] * 0.125f;
            float mx = fmaxf(fmaxf(s0, s1), fmaxf(s2, s3));
            mx = fmaxf(mx, __shfl_xor(mx, 1));
            mx = fmaxf(mx, __shfl_xor(mx, 2));
            mx = fmaxf(mx, __shfl_xor(mx, 4));
            mx = fmaxf(mx, __shfl_xor(mx, 8));
            float e0 = __expf(s0 - mx), e1 = __expf(s1 - mx);
            float e2 = __expf(s2 - mx), e3 = __expf(s3 - mx);
            float sm = e0 + e1 + e2 + e3;
            sm += __shfl_xor(sm, 1);
            sm += __shfl_xor(sm, 2);
            sm += __shfl_xor(sm, 4);
            sm += __shfl_xor(sm, 8);
            const float inv = 1.0f / sm;
            short* pr = &pl[(m * 16 + hi * 4 + j) * 72 + lo];
            pr[0]  = bf16s(e0 * inv);
            pr[16] = bf16s(e1 * inv);
            pr[32] = bf16s(e2 * inv);
            pr[48] = bf16s(e3 * inv);
        }
    }
    __syncthreads();

    // O = P @ V  (A = P from LDS, B = V^T rows from global)
    const short* vg = reinterpret_cast<const short*>(vt) + ((size_t)(n * NHEAD + h) << 12);
    f32x4 o[4][4] = {};
#pragma unroll
    for (int ks = 0; ks < 2; ++ks) {
        const int kc = ks * 32 + hi * 8;
        bf16x8 pa[4], bv[4];
#pragma unroll
        for (int m = 0; m < 4; ++m)
            pa[m] = *reinterpret_cast<const bf16x8*>(&pl[(m * 16 + lo) * 72 + kc]);
#pragma unroll
        for (int nn = 0; nn < 4; ++nn)
            bv[nn] = *reinterpret_cast<const bf16x8*>(vg + (nn * 16 + lo) * 64 + kc);
#pragma unroll
        for (int m = 0; m < 4; ++m)
#pragma unroll
            for (int nn = 0; nn < 4; ++nn)
                o[m][nn] = __builtin_amdgcn_mfma_f32_16x16x32_bf16(
                    pa[m], bv[nn], o[m][nn], 0, 0, 0);
    }

#pragma unroll
    for (int m = 0; m < 4; ++m)
#pragma unroll
        for (int nn = 0; nn < 4; ++nn)
#pragma unroll
            for (int j = 0; j < 4; ++j)
                out[(size_t)(n * 64 + m * 16 + hi * 4 + j) * DD + h * 64 + nn * 16 + lo] =
                    __float2bfloat16(o[m][nn][j]);
}

// ---------------------------------------------------------------------------
// SAUTE part 1: P[row][u] = mask(b,t,u) * (tok[row,:] . v[b,u,:])
__global__ __launch_bounds__(256) void saute_p_kernel(
    const float* __restrict__ X, const float* __restrict__ vmat,
    const int* __restrict__ spk, float* __restrict__ P)
{
    __shared__ float toks[8 * DD];
    __shared__ unsigned vls[32 * 392];
    const int row0 = blockIdx.x * 8;
    const int bt = row0 >> 6, b = bt >> 5, t = bt & 31;
    const int tid = threadIdx.x;

    for (int i = tid; i < 8 * DD; i += 256)
        toks[i] = X[(size_t)row0 * DD + i];
    const float2* v2 = reinterpret_cast<const float2*>(vmat + (size_t)b * TT * DD);
    for (int i = tid; i < 32 * 384; i += 256) {
        int u = i / 384, j = i - u * 384;
        float2 f = v2[i];
        vls[u * 392 + j] = pack_bf16(f.x, f.y);
    }
    __syncthreads();

    const int u = tid >> 3, l8 = tid & 7;
    const int sb = spk[bt];
    const bool mk = (u <= t) && (spk[b * TT + u] == sb);
#pragma unroll
    for (int r = 0; r < 8; ++r) {
        float s = 0.f;
        const float* tr = &toks[r * DD];
        const unsigned* vr = &vls[u * 392];
        for (int j = l8; j < 384; j += 8) {
            unsigned pk = vr[j];
            s = fmaf(tr[2 * j],     __uint_as_float(pk << 16),          s);
            s = fmaf(tr[2 * j + 1], __uint_as_float(pk & 0xffff0000u), s);
        }
        s += __shfl_down(s, 4, 8);
        s += __shfl_down(s, 2, 8);
        s += __shfl_down(s, 1, 8);
        if (l8 == 0) P[(size_t)(row0 + r) * 32 + u] = mk ? s : 0.f;
    }
}

// ---------------------------------------------------------------------------
// SAUTE part 2: ctx[row,:] = tok[row,:] + sum_u P[row][u] * k[b,u,:]
__global__ __launch_bounds__(256) void saute_ctx_kernel(
    float* __restrict__ X, __hip_bfloat16* __restrict__ Xb,
    const float* __restrict__ kmat, const float* __restrict__ P)
{
    __shared__ unsigned kls[32 * 384];
    __shared__ float pls[8 * 32];
    const int row0 = blockIdx.x * 8;
    const int bt = row0 >> 6, b = bt >> 5;
    const int tid = threadIdx.x;

    const float2* k2 = reinterpret_cast<const float2*>(kmat + (size_t)b * TT * DD);
    for (int i = tid; i < 32 * 384; i += 256) {
        float2 f = k2[i];
        kls[i] = pack_bf16(f.x, f.y);
    }
    pls[tid] = P[(size_t)row0 * 32 + tid];
    __syncthreads();

    float acc[3][8];
#pragma unroll
    for (int c = 0; c < 3; ++c)
#pragma unroll
        for (int r = 0; r < 8; ++r)
            acc[c][r] = X[(size_t)(row0 + r) * DD + tid + 256 * c];

    const int par = tid & 1;
    for (int u = 0; u < 32; ++u) {
        float pv[8];
#pragma unroll
        for (int r = 0; r < 8; ++r) pv[r] = pls[r * 32 + u];
#pragma unroll
        for (int c = 0; c < 3; ++c) {
            unsigned pk = kls[u * 384 + ((tid + 256 * c) >> 1)];
            float kv = par ? __uint_as_float(pk & 0xffff0000u)
                           : __uint_as_float(pk << 16);
#pragma unroll
            for (int r = 0; r < 8; ++r)
                acc[c][r] = fmaf(pv[r], kv, acc[c][r]);
        }
    }
#pragma unroll
    for (int c = 0; c < 3; ++c)
#pragma unroll
        for (int r = 0; r < 8; ++r) {
            size_t o = (size_t)(row0 + r) * DD + tid + 256 * c;
            X[o]  = acc[c][r];
            Xb[o] = __float2bfloat16(acc[c][r]);
        }
}

// ---------------------------------------------------------------------------
// x = LayerNorm(x + y) * g + b; x fp32 in place, y bf16; also emit bf16 copy.
__global__ __launch_bounds__(256) void add_ln_kernel(
    float* __restrict__ x, const __hip_bfloat16* __restrict__ y,
    const float* __restrict__ g, const float* __restrict__ bb,
    __hip_bfloat16* __restrict__ xb)
{
    const int row = blockIdx.x;
    const int tid = threadIdx.x;
    __shared__ float red[4];
    __shared__ float stat[2];
    const size_t base = (size_t)row * DD;

    float v0 = x[base + tid]       + __bfloat162float(y[base + tid]);
    float v1 = x[base + tid + 256] + __bfloat162float(y[base + tid + 256]);
    float v2 = x[base + tid + 512] + __bfloat162float(y[base + tid + 512]);

    float s = v0 + v1 + v2;
#pragma unroll
    for (int off = 32; off > 0; off >>= 1) s += __shfl_down(s, off);
    if ((tid & 63) == 0) red[tid >> 6] = s;
    __syncthreads();
    if (tid == 0) stat[0] = (red[0] + red[1] + red[2] + red[3]) * (1.0f / (float)DD);
    __syncthreads();
    const float mu = stat[0];

    float d0 = v0 - mu, d1 = v1 - mu, d2 = v2 - mu;
    float q = d0 * d0 + d1 * d1 + d2 * d2;
    __syncthreads();
#pragma unroll
    for (int off = 32; off > 0; off >>= 1) q += __shfl_down(q, off);
    if ((tid & 63) == 0) red[tid >> 6] = q;
    __syncthreads();
    if (tid == 0) stat[1] = (red[0] + red[1] + red[2] + red[3]) * (1.0f / (float)DD);
    __syncthreads();
    const float rstd = rsqrtf(stat[1] + 1e-5f);

    float o0 = d0 * rstd * g[tid]       + bb[tid];
    float o1 = d1 * rstd * g[tid + 256] + bb[tid + 256];
    float o2 = d2 * rstd * g[tid + 512] + bb[tid + 512];
    x[base + tid]        = o0;
    x[base + tid + 256]  = o1;
    x[base + tid + 512]  = o2;
    xb[base + tid]       = __float2bfloat16(o0);
    xb[base + tid + 256] = __float2bfloat16(o1);
    xb[base + tid + 512] = __float2bfloat16(o2);
}

// ---------------------------------------------------------------------------
extern "C" void kernel_launch(void* const* d_in, const int* in_sizes, int n_in,
                              void* d_out, int out_size, void* d_ws, size_t ws_size,
                              hipStream_t stream) {
    (void)in_sizes; (void)n_in; (void)out_size; (void)ws_size;
    const float* te  = (const float*)d_in[0];
    const int*   spk = (const int*)  d_in[1];
    const float* Wq  = (const float*)d_in[2];
    const float* Wk  = (const float*)d_in[3];
    const float* Wv  = (const float*)d_in[4];
    const float* ipw = (const float*)d_in[5];
    const float* ipb = (const float*)d_in[6];
    const float* ow  = (const float*)d_in[7];
    const float* ob  = (const float*)d_in[8];
    const float* g1  = (const float*)d_in[9];
    const float* b1  = (const float*)d_in[10];
    const float* f1w = (const float*)d_in[11];
    const float* f1b = (const float*)d_in[12];
    const float* f2w = (const float*)d_in[13];
    const float* f2b = (const float*)d_in[14];
    const float* g2  = (const float*)d_in[15];
    const float* b2  = (const float*)d_in[16];

    float* X = (float*)d_out;                          // residual stream (8192,768)

    // ws layout (bf16 region first, all byte offsets multiples of 16)
    __hip_bfloat16* wsb   = (__hip_bfloat16*)d_ws;
    __hip_bfloat16* Wq_b  = wsb;                               //   589,824
    __hip_bfloat16* ipw_b = Wq_b  + 589824;                    // 3,538,944
    __hip_bfloat16* ow_b  = ipw_b + 3538944;                   // 1,179,648
    __hip_bfloat16* f1w_b = ow_b  + 1179648;                   // 3,145,728
    __hip_bfloat16* f2w_b = f1w_b + 3145728;                   // 3,145,728
    __hip_bfloat16* Xb    = f2w_b + 3145728;                   // 6,291,456
    __hip_bfloat16* SCR   = Xb    + 6291456;                   // 12,582,912 (q|k, ld 1536) / ffn-hidden (ld 2048)
    __hip_bfloat16* Vt    = SCR   + 12582912;                  // 6,291,456 (V^T per head)
    __hip_bfloat16* Ab    = Vt    + 6291456;                   // 6,291,456 (attn out; TE cast early)
    __hip_bfloat16* Yb    = Ab    + 6291456;                   // 6,291,456 (gemm out for residual)
    float* fws = (float*)(Yb + 6291456);
    float* edu = fws;                                          // 98,304
    float* kb  = edu + BTN * DD;                               // 98,304
    float* vb  = kb  + BTN * DD;                               // 98,304
    float* Pbuf= vb  + BTN * DD;                               // 262,144

    // 1. te prep (bf16 cast into Ab + edu mean) and weight casts
    te_prep_kernel<<<(BTN * DD) / 256, 256, 0, stream>>>(te, Ab, edu);
    cast_bf16_kernel<<<(589824/4 + 255)/256, 256, 0, stream>>>(Wq, Wq_b, 589824/4);
    cast_bf16_kernel<<<(3538944/4 + 255)/256, 256, 0, stream>>>(ipw, ipw_b, 3538944/4);
    cast_bf16_kernel<<<(1179648/4 + 255)/256, 256, 0, stream>>>(ow, ow_b, 1179648/4);
    cast_bf16_kernel<<<(3145728/4 + 255)/256, 256, 0, stream>>>(f1w, f1w_b, 3145728/4);
    cast_bf16_kernel<<<(3145728/4 + 255)/256, 256, 0, stream>>>(f2w, f2w_b, 3145728/4);

    // 2. tiny fp32 k/v projections
    gemm_abt_kernel<<<dim3(DD/GBN, BTN/GBM), 256, 0, stream>>>(edu, Wk, kb, BTN, DD, DD);
    gemm_abt_kernel<<<dim3(DD/GBN, BTN/GBM), 256, 0, stream>>>(edu, Wv, vb, BTN, DD, DD);

    // 3. tok = TE @ Wq^T  (fp32 out -> X)
    gemm_bf16_kernel<0,0,0><<<dim3(DD/128, ROWS/128), 256, 0, stream>>>(
        Ab, Wq_b, nullptr, X, nullptr, ROWS, DD, DD, DD);

    // 4. SAUTE: P = masked tok.v, then ctx = tok + P @ k (in place on X, + bf16)
    saute_p_kernel<<<ROWS/8, 256, 0, stream>>>(X, vb, spk, Pbuf);
    saute_ctx_kernel<<<ROWS/8, 256, 0, stream>>>(X, Xb, kb, Pbuf);

    // 5. transformer layers
    for (int l = 0; l < NLAYERS; ++l) {
        const __hip_bfloat16* ipw_l = ipw_b + (size_t)l * 3 * DD * DD;
        const __hip_bfloat16* ow_l  = ow_b  + (size_t)l * DD * DD;
        const __hip_bfloat16* f1w_l = f1w_b + (size_t)l * DFF * DD;
        const __hip_bfloat16* f2w_l = f2w_b + (size_t)l * DD * DFF;

        // qkv: Q|K -> SCR (ld 1536), V -> Vt (transposed per head)
        gemm_bf16_kernel<1,0,1><<<dim3(3*DD/128, ROWS/128), 256, 0, stream>>>(
            Xb, ipw_l, ipb + (size_t)l * 3 * DD, SCR, Vt, ROWS, 3*DD, DD, 1536);
        // attention -> Ab (bf16)
        attn_mfma_kernel<<<dim3(BTN, NHEAD), 64, 0, stream>>>(SCR, Vt, Ab);
        // out proj -> Yb (bf16)
        gemm_bf16_kernel<1,0,0><<<dim3(DD/128, ROWS/128), 256, 0, stream>>>(
            Ab, ow_l, ob + (size_t)l * DD, Yb, nullptr, ROWS, DD, DD, DD);
        // X = LN(X + Yb)
        add_ln_kernel<<<ROWS, 256, 0, stream>>>(X, Yb, g1 + (size_t)l * DD, b1 + (size_t)l * DD, Xb);
        // H = relu(Xb @ ff1^T + b) -> SCR (bf16, ld 2048)
        gemm_bf16_kernel<1,1,0><<<dim3(DFF/128, ROWS/128), 256, 0, stream>>>(
            Xb, f1w_l, f1b + (size_t)l * DFF, SCR, nullptr, ROWS, DFF, DD, DFF);
        // P = H @ ff2^T + b -> Yb (bf16), K=2048
        gemm_bf16_kernel<1,0,0><<<dim3(DD/128, ROWS/128), 256, 0, stream>>>(
            SCR, f2w_l, f2b + (size_t)l * DD, Yb, nullptr, ROWS, DD, DFF, DD);
        // X = LN(X + Yb)
        add_ln_kernel<<<ROWS, 256, 0, stream>>>(X, Yb, g2 + (size_t)l * DD, b2 + (size_t)l * DD, Xb);
    }
}

// Round 9
// 562.584 us; speedup vs baseline: 7.7249x; 1.0906x over previous
//
#include <hip/hip_runtime.h>
#include <hip/hip_bf16.h>

// Problem constants
#define BB 4
#define TT 32
#define LL 64
#define DD 768
#define NHEAD 12
#define DH 64
#define DFF 2048
#define NLAYERS 2
#define ROWS (BB*TT*LL)      // 8192
#define BTN  (BB*TT)         // 128

typedef __attribute__((ext_vector_type(8))) short bf16x8;
typedef __attribute__((ext_vector_type(4))) float f32x4;

// XOR swizzle for 128x32-short LDS tiles: row r (0..127), 16B chunk c (0..3).
__device__ __forceinline__ int swz(int r, int c) {
    return r * 32 + ((c ^ ((r >> 1) & 3)) << 3);
}

__device__ __forceinline__ unsigned pack_bf16(float a, float b) {
    __hip_bfloat16 h0 = __float2bfloat16(a);
    __hip_bfloat16 h1 = __float2bfloat16(b);
    return (unsigned)*reinterpret_cast<unsigned short*>(&h0) |
           ((unsigned)*reinterpret_cast<unsigned short*>(&h1) << 16);
}

__device__ __forceinline__ short bf16s(float a) {
    __hip_bfloat16 h = __float2bfloat16(a);
    return *reinterpret_cast<short*>(&h);
}

// ---------------------------------------------------------------------------
// fp32 -> bf16 cast, 4 elements / thread.
__global__ __launch_bounds__(256) void cast_bf16_kernel(
    const float* __restrict__ in, __hip_bfloat16* __restrict__ out, int n4)
{
    int i = blockIdx.x * 256 + threadIdx.x;
    if (i >= n4) return;
    float4 v = reinterpret_cast<const float4*>(in)[i];
    ushort4 o;
    __hip_bfloat16 h0 = __float2bfloat16(v.x);
    __hip_bfloat16 h1 = __float2bfloat16(v.y);
    __hip_bfloat16 h2 = __float2bfloat16(v.z);
    __hip_bfloat16 h3 = __float2bfloat16(v.w);
    o.x = *reinterpret_cast<unsigned short*>(&h0);
    o.y = *reinterpret_cast<unsigned short*>(&h1);
    o.z = *reinterpret_cast<unsigned short*>(&h2);
    o.w = *reinterpret_cast<unsigned short*>(&h3);
    reinterpret_cast<ushort4*>(out)[i] = o;
}

// ---------------------------------------------------------------------------
// Fused: teb = bf16(te), edu = mean over L of te. One read of te.
__global__ __launch_bounds__(256) void te_prep_kernel(
    const float* __restrict__ te, __hip_bfloat16* __restrict__ teb,
    float* __restrict__ edu)
{
    int idx = blockIdx.x * 256 + threadIdx.x;
    int bt = idx / DD;
    int d  = idx - bt * DD;
    const float* p = te + ((size_t)bt * LL) * DD + d;
    __hip_bfloat16* q = teb + ((size_t)bt * LL) * DD + d;
    float s = 0.f;
#pragma unroll
    for (int l = 0; l < LL; ++l) {
        float v = p[(size_t)l * DD];
        s += v;
        q[(size_t)l * DD] = __float2bfloat16(v);
    }
    edu[idx] = s * (1.0f / (float)LL);
}

// ---------------------------------------------------------------------------
// Small fp32-in GEMM, bf16 out (tiny M=128 k/v projections):
// C[M,N] = bf16(A[M,K] @ B[N,K]^T)
#define GBM 64
#define GBN 64
#define GBK 16
__global__ __launch_bounds__(256) void gemm_abt_kernel(
    const float* __restrict__ A, const float* __restrict__ B,
    __hip_bfloat16* __restrict__ C, int M, int N, int K)
{
    __shared__ float As[GBM][GBK + 1];
    __shared__ float Bs[GBN][GBK + 1];
    const int bm = blockIdx.y * GBM;
    const int bn = blockIdx.x * GBN;
    const int tid = threadIdx.x;
    const int tx = tid & 15;
    const int ty = tid >> 4;
    const int lr = tid >> 2;
    const int lc = (tid & 3) << 2;

    float acc[4][4] = {};

    for (int k0 = 0; k0 < K; k0 += GBK) {
        float4 va = *reinterpret_cast<const float4*>(A + (size_t)(bm + lr) * K + k0 + lc);
        float4 vb = *reinterpret_cast<const float4*>(B + (size_t)(bn + lr) * K + k0 + lc);
        As[lr][lc + 0] = va.x; As[lr][lc + 1] = va.y;
        As[lr][lc + 2] = va.z; As[lr][lc + 3] = va.w;
        Bs[lr][lc + 0] = vb.x; Bs[lr][lc + 1] = vb.y;
        Bs[lr][lc + 2] = vb.z; Bs[lr][lc + 3] = vb.w;
        __syncthreads();
#pragma unroll
        for (int kk = 0; kk < GBK; ++kk) {
            float a[4], b[4];
#pragma unroll
            for (int i = 0; i < 4; ++i) a[i] = As[ty * 4 + i][kk];
#pragma unroll
            for (int j = 0; j < 4; ++j) b[j] = Bs[tx * 4 + j][kk];
#pragma unroll
            for (int i = 0; i < 4; ++i)
#pragma unroll
                for (int j = 0; j < 4; ++j)
                    acc[i][j] = fmaf(a[i], b[j], acc[i][j]);
        }
        __syncthreads();
    }
#pragma unroll
    for (int i = 0; i < 4; ++i)
#pragma unroll
        for (int j = 0; j < 4; ++j)
            C[(size_t)(bm + ty * 4 + i) * N + bn + tx * 4 + j] =
                __float2bfloat16(acc[i][j]);
}

// ---------------------------------------------------------------------------
// bf16 MFMA GEMM: reg-staged, double-buffered LDS, XOR-swizzled.
// C[M,N] = A[M,K] @ B[N,K]^T (+bias)(+relu). BM=BN=128, BK=32, 256 thr.
// QKV mode: cols < 1536 -> Cout (ld 1536); cols >= 1536 (the V third)
// stored TRANSPOSED per head into Vout[n][h][d][l].
template<int OUT_BF16, int RELU, int QKV>
__global__ __launch_bounds__(256) void gemm_bf16_kernel(
    const __hip_bfloat16* __restrict__ A,
    const __hip_bfloat16* __restrict__ B,
    const float* __restrict__ bias,
    void* __restrict__ Cout,
    __hip_bfloat16* __restrict__ Vout,
    int M, int N, int K, int ldC)
{
    __shared__ short lA[2][4096];
    __shared__ short lB[2][4096];
    const int tid  = threadIdx.x;
    const int lane = tid & 63;
    const int w    = tid >> 6;
    const int wr   = w >> 1, wc = w & 1;
    const int bm = blockIdx.y * 128;
    const int bn = blockIdx.x * 128;

    const int sr  = tid >> 2;
    const int cw  = tid & 3;
    const int sco = cw << 3;

    const int wo0 = swz(sr, cw);
    const int wo1 = swz(sr + 64, cw);
    int roA[4], roB[4];
#pragma unroll
    for (int m = 0; m < 4; ++m)
        roA[m] = swz(wr * 64 + m * 16 + (lane & 15), lane >> 4);
#pragma unroll
    for (int n = 0; n < 4; ++n)
        roB[n] = swz(wc * 64 + n * 16 + (lane & 15), lane >> 4);

    const short* Ag = reinterpret_cast<const short*>(A);
    const short* Bg = reinterpret_cast<const short*>(B);

    f32x4 acc[4][4] = {};

    bf16x8 ra0 = *reinterpret_cast<const bf16x8*>(Ag + (size_t)(bm + sr) * K + sco);
    bf16x8 ra1 = *reinterpret_cast<const bf16x8*>(Ag + (size_t)(bm + 64 + sr) * K + sco);
    bf16x8 rb0 = *reinterpret_cast<const bf16x8*>(Bg + (size_t)(bn + sr) * K + sco);
    bf16x8 rb1 = *reinterpret_cast<const bf16x8*>(Bg + (size_t)(bn + 64 + sr) * K + sco);
    *reinterpret_cast<bf16x8*>(&lA[0][wo0]) = ra0;
    *reinterpret_cast<bf16x8*>(&lA[0][wo1]) = ra1;
    *reinterpret_cast<bf16x8*>(&lB[0][wo0]) = rb0;
    *reinterpret_cast<bf16x8*>(&lB[0][wo1]) = rb1;
    __syncthreads();

    const int NT = K >> 5;
    int cur = 0;
    for (int t = 0; t < NT; ++t) {
        const bool nx = (t + 1 < NT);
        if (nx) {
            const int kn = (t + 1) << 5;
            ra0 = *reinterpret_cast<const bf16x8*>(Ag + (size_t)(bm + sr) * K + kn + sco);
            ra1 = *reinterpret_cast<const bf16x8*>(Ag + (size_t)(bm + 64 + sr) * K + kn + sco);
            rb0 = *reinterpret_cast<const bf16x8*>(Bg + (size_t)(bn + sr) * K + kn + sco);
            rb1 = *reinterpret_cast<const bf16x8*>(Bg + (size_t)(bn + 64 + sr) * K + kn + sco);
        }

        bf16x8 af[4], bfr[4];
#pragma unroll
        for (int m = 0; m < 4; ++m)
            af[m] = *reinterpret_cast<const bf16x8*>(&lA[cur][roA[m]]);
#pragma unroll
        for (int n = 0; n < 4; ++n)
            bfr[n] = *reinterpret_cast<const bf16x8*>(&lB[cur][roB[n]]);
#pragma unroll
        for (int m = 0; m < 4; ++m)
#pragma unroll
            for (int n = 0; n < 4; ++n)
                acc[m][n] = __builtin_amdgcn_mfma_f32_16x16x32_bf16(
                    af[m], bfr[n], acc[m][n], 0, 0, 0);

        if (nx) {
            *reinterpret_cast<bf16x8*>(&lA[cur ^ 1][wo0]) = ra0;
            *reinterpret_cast<bf16x8*>(&lA[cur ^ 1][wo1]) = ra1;
            *reinterpret_cast<bf16x8*>(&lB[cur ^ 1][wo0]) = rb0;
            *reinterpret_cast<bf16x8*>(&lB[cur ^ 1][wo1]) = rb1;
        }
        __syncthreads();
        cur ^= 1;
    }

    const int crow = (lane >> 4) * 4;
    const int ccol = lane & 15;
#pragma unroll
    for (int n = 0; n < 4; ++n) {
        const int col = bn + wc * 64 + n * 16 + ccol;
        const float bv = bias ? bias[col] : 0.f;
        if (QKV && col >= 1536) {
            const int hh = (col - 1536) >> 6;
            const int d  = (col - 1536) & 63;
#pragma unroll
            for (int m = 0; m < 4; ++m) {
                const int row0 = bm + wr * 64 + m * 16 + crow;
#pragma unroll
                for (int j = 0; j < 4; ++j) {
                    const int row = row0 + j;
                    const int ni = row >> 6, ll = row & 63;
                    Vout[(((size_t)ni * NHEAD + hh) << 12) + (d << 6) + ll] =
                        __float2bfloat16(acc[m][n][j] + bv);
                }
            }
        } else {
#pragma unroll
            for (int m = 0; m < 4; ++m) {
                const int row0 = bm + wr * 64 + m * 16 + crow;
#pragma unroll
                for (int j = 0; j < 4; ++j) {
                    float v = acc[m][n][j] + bv;
                    if (RELU) v = fmaxf(v, 0.f);
                    if (OUT_BF16)
                        reinterpret_cast<__hip_bfloat16*>(Cout)[(size_t)(row0 + j) * ldC + col] =
                            __float2bfloat16(v);
                    else
                        reinterpret_cast<float*>(Cout)[(size_t)(row0 + j) * ldC + col] = v;
                }
            }
        }
    }
}

// ---------------------------------------------------------------------------
// MFMA attention: one wave per (n,h). qk: (8192,1536) bf16 Q|K rows;
// vt: (128,12,64,64) bf16 V^T; out: (8192,768) bf16.
__global__ __launch_bounds__(64) void attn_mfma_kernel(
    const __hip_bfloat16* __restrict__ qk,
    const __hip_bfloat16* __restrict__ vt,
    __hip_bfloat16* __restrict__ out)
{
    const int n = blockIdx.x, h = blockIdx.y;
    const int lane = threadIdx.x;
    const int lo = lane & 15, hi = lane >> 4;
    __shared__ short pl[64 * 72];

    const short* qg = reinterpret_cast<const short*>(qk) + (size_t)(n * 64) * 1536 + h * 64;

    f32x4 acc[4][4] = {};
#pragma unroll
    for (int ks = 0; ks < 2; ++ks) {
        const int kc = ks * 32 + hi * 8;
        bf16x8 af[4], bk[4];
#pragma unroll
        for (int m = 0; m < 4; ++m)
            af[m] = *reinterpret_cast<const bf16x8*>(qg + (size_t)(m * 16 + lo) * 1536 + kc);
#pragma unroll
        for (int nn = 0; nn < 4; ++nn)
            bk[nn] = *reinterpret_cast<const bf16x8*>(qg + 768 + (size_t)(nn * 16 + lo) * 1536 + kc);
#pragma unroll
        for (int m = 0; m < 4; ++m)
#pragma unroll
            for (int nn = 0; nn < 4; ++nn)
                acc[m][nn] = __builtin_amdgcn_mfma_f32_16x16x32_bf16(
                    af[m], bk[nn], acc[m][nn], 0, 0, 0);
    }

#pragma unroll
    for (int m = 0; m < 4; ++m) {
#pragma unroll
        for (int j = 0; j < 4; ++j) {
            float s0 = acc[m][0][j] * 0.125f;
            float s1 = acc[m][1][j] * 0.125f;
            float s2 = acc[m][2][j] * 0.125f;
            float s3 = acc[m][3][j] * 0.125f;
            float mx = fmaxf(fmaxf(s0, s1), fmaxf(s2, s3));
            mx = fmaxf(mx, __shfl_xor(mx, 1));
            mx = fmaxf(mx, __shfl_xor(mx, 2));
            mx = fmaxf(mx, __shfl_xor(mx, 4));
            mx = fmaxf(mx, __shfl_xor(mx, 8));
            float e0 = __expf(s0 - mx), e1 = __expf(s1 - mx);
            float e2 = __expf(s2 - mx), e3 = __expf(s3 - mx);
            float sm = e0 + e1 + e2 + e3;
            sm += __shfl_xor(sm, 1);
            sm += __shfl_xor(sm, 2);
            sm += __shfl_xor(sm, 4);
            sm += __shfl_xor(sm, 8);
            const float inv = 1.0f / sm;
            short* pr = &pl[(m * 16 + hi * 4 + j) * 72 + lo];
            pr[0]  = bf16s(e0 * inv);
            pr[16] = bf16s(e1 * inv);
            pr[32] = bf16s(e2 * inv);
            pr[48] = bf16s(e3 * inv);
        }
    }
    __syncthreads();

    const short* vg = reinterpret_cast<const short*>(vt) + ((size_t)(n * NHEAD + h) << 12);
    f32x4 o[4][4] = {};
#pragma unroll
    for (int ks = 0; ks < 2; ++ks) {
        const int kc = ks * 32 + hi * 8;
        bf16x8 pa[4], bv[4];
#pragma unroll
        for (int m = 0; m < 4; ++m)
            pa[m] = *reinterpret_cast<const bf16x8*>(&pl[(m * 16 + lo) * 72 + kc]);
#pragma unroll
        for (int nn = 0; nn < 4; ++nn)
            bv[nn] = *reinterpret_cast<const bf16x8*>(vg + (nn * 16 + lo) * 64 + kc);
#pragma unroll
        for (int m = 0; m < 4; ++m)
#pragma unroll
            for (int nn = 0; nn < 4; ++nn)
                o[m][nn] = __builtin_amdgcn_mfma_f32_16x16x32_bf16(
                    pa[m], bv[nn], o[m][nn], 0, 0, 0);
    }

#pragma unroll
    for (int m = 0; m < 4; ++m)
#pragma unroll
        for (int nn = 0; nn < 4; ++nn)
#pragma unroll
            for (int j = 0; j < 4; ++j)
                out[(size_t)(n * 64 + m * 16 + hi * 4 + j) * DD + h * 64 + nn * 16 + lo] =
                    __float2bfloat16(o[m][nn][j]);
}

// ---------------------------------------------------------------------------
// SAUTE part 1 (MFMA): P[row][u] = mask * (tok[row,:].v[b,u,:]).
// One wave per 64-row group (one bt). grid=128, block=64.
// Xb: (8192,768) bf16 tok; vbb: (128,768) bf16; P: (8192,32) bf16.
__global__ __launch_bounds__(64) void saute_p_mfma_kernel(
    const __hip_bfloat16* __restrict__ Xb,
    const __hip_bfloat16* __restrict__ vbb,
    const int* __restrict__ spk,
    __hip_bfloat16* __restrict__ P)
{
    const int lane = threadIdx.x;
    const int lo = lane & 15, hi = lane >> 4;
    const int row0 = blockIdx.x * 64;
    const int bt = row0 >> 6;
    const int b  = bt >> 5, t = bt & 31;

    const short* Ag = reinterpret_cast<const short*>(Xb) + (size_t)row0 * DD;
    const short* Bg = reinterpret_cast<const short*>(vbb) + (size_t)(b * TT) * DD;

    f32x4 acc[4][2] = {};
    for (int ks = 0; ks < 24; ++ks) {
        const int kc = ks * 32 + hi * 8;
        bf16x8 af[4], bv[2];
#pragma unroll
        for (int m = 0; m < 4; ++m)
            af[m] = *reinterpret_cast<const bf16x8*>(Ag + (size_t)(m * 16 + lo) * DD + kc);
#pragma unroll
        for (int nn = 0; nn < 2; ++nn)
            bv[nn] = *reinterpret_cast<const bf16x8*>(Bg + (size_t)(nn * 16 + lo) * DD + kc);
#pragma unroll
        for (int m = 0; m < 4; ++m)
#pragma unroll
            for (int nn = 0; nn < 2; ++nn)
                acc[m][nn] = __builtin_amdgcn_mfma_f32_16x16x32_bf16(
                    af[m], bv[nn], acc[m][nn], 0, 0, 0);
    }

    const int st = spk[bt];
#pragma unroll
    for (int nn = 0; nn < 2; ++nn) {
        const int u = nn * 16 + lo;
        const bool mk = (u <= t) && (spk[b * TT + u] == st);
#pragma unroll
        for (int m = 0; m < 4; ++m)
#pragma unroll
            for (int j = 0; j < 4; ++j) {
                const int row = row0 + m * 16 + hi * 4 + j;
                P[(size_t)row * 32 + u] =
                    mk ? __float2bfloat16(acc[m][nn][j]) : __float2bfloat16(0.f);
            }
    }
}

// ---------------------------------------------------------------------------
// SAUTE part 2: ctx = tok + P @ k, in place on bf16 Xb.
// 8 rows / block, 256 threads; thread t: row=t>>5, 12 bf16-pairs.
__global__ __launch_bounds__(256) void saute_ctx_kernel(
    __hip_bfloat16* __restrict__ Xb,
    const __hip_bfloat16* __restrict__ kbb,
    const __hip_bfloat16* __restrict__ P)
{
    __shared__ unsigned kls[32 * 384];      // 49.2 KB bf16 pairs
    __shared__ float pls[8 * 32];
    const int row0 = blockIdx.x * 8;
    const int b = row0 >> 11;
    const int tid = threadIdx.x;

    const unsigned* k2 = reinterpret_cast<const unsigned*>(kbb + (size_t)b * TT * DD);
    for (int i = tid; i < 32 * 384; i += 256) kls[i] = k2[i];
    pls[tid] = __bfloat162float(P[(size_t)row0 * 32 + tid]);
    __syncthreads();

    const int r = tid >> 5;          // 0..7
    const int l32 = tid & 31;        // pair lane
    unsigned* xrow = reinterpret_cast<unsigned*>(Xb + (size_t)(row0 + r) * DD);

    float2 acc[12];
#pragma unroll
    for (int c = 0; c < 12; ++c) {
        unsigned pk = xrow[l32 + 32 * c];
        acc[c].x = __uint_as_float(pk << 16);
        acc[c].y = __uint_as_float(pk & 0xffff0000u);
    }
    for (int u = 0; u < 32; ++u) {
        const float pv = pls[r * 32 + u];
        const unsigned* kr = &kls[u * 384];
#pragma unroll
        for (int c = 0; c < 12; ++c) {
            unsigned pk = kr[l32 + 32 * c];
            acc[c].x = fmaf(pv, __uint_as_float(pk << 16),          acc[c].x);
            acc[c].y = fmaf(pv, __uint_as_float(pk & 0xffff0000u), acc[c].y);
        }
    }
#pragma unroll
    for (int c = 0; c < 12; ++c)
        xrow[l32 + 32 * c] = pack_bf16(acc[c].x, acc[c].y);
}

// ---------------------------------------------------------------------------
// LayerNorm over bf16 residual: xb = bf16(LN(xb + y)); FINAL also writes fp32.
// 192 threads, 4 contiguous bf16 per thread.
template<int FINAL>
__global__ __launch_bounds__(192) void add_ln_kernel(
    __hip_bfloat16* __restrict__ xb, const __hip_bfloat16* __restrict__ y,
    const float* __restrict__ g, const float* __restrict__ bb,
    float* __restrict__ xf)
{
    const int row = blockIdx.x;
    const int tid = threadIdx.x;
    __shared__ float red[3];
    __shared__ float stat[2];
    const size_t base = (size_t)row * DD + tid * 4;

    uint2 xv = *reinterpret_cast<const uint2*>(xb + base);
    uint2 yv = *reinterpret_cast<const uint2*>(y + base);
    float v[4];
    v[0] = __uint_as_float(xv.x << 16)         + __uint_as_float(yv.x << 16);
    v[1] = __uint_as_float(xv.x & 0xffff0000u) + __uint_as_float(yv.x & 0xffff0000u);
    v[2] = __uint_as_float(xv.y << 16)         + __uint_as_float(yv.y << 16);
    v[3] = __uint_as_float(xv.y & 0xffff0000u) + __uint_as_float(yv.y & 0xffff0000u);

    float s = v[0] + v[1] + v[2] + v[3];
#pragma unroll
    for (int off = 32; off > 0; off >>= 1) s += __shfl_down(s, off);
    if ((tid & 63) == 0) red[tid >> 6] = s;
    __syncthreads();
    if (tid == 0) stat[0] = (red[0] + red[1] + red[2]) * (1.0f / (float)DD);
    __syncthreads();
    const float mu = stat[0];

    float d[4];
    float q = 0.f;
#pragma unroll
    for (int i = 0; i < 4; ++i) { d[i] = v[i] - mu; q += d[i] * d[i]; }
    __syncthreads();
#pragma unroll
    for (int off = 32; off > 0; off >>= 1) q += __shfl_down(q, off);
    if ((tid & 63) == 0) red[tid >> 6] = q;
    __syncthreads();
    if (tid == 0) stat[1] = (red[0] + red[1] + red[2]) * (1.0f / (float)DD);
    __syncthreads();
    const float rstd = rsqrtf(stat[1] + 1e-5f);

    float o[4];
#pragma unroll
    for (int i = 0; i < 4; ++i)
        o[i] = d[i] * rstd * g[tid * 4 + i] + bb[tid * 4 + i];

    if (FINAL) {
        float4 f4 = make_float4(o[0], o[1], o[2], o[3]);
        *reinterpret_cast<float4*>(xf + base) = f4;
    } else {
        uint2 ov;
        ov.x = pack_bf16(o[0], o[1]);
        ov.y = pack_bf16(o[2], o[3]);
        *reinterpret_cast<uint2*>(xb + base) = ov;
    }
}

// ---------------------------------------------------------------------------
extern "C" void kernel_launch(void* const* d_in, const int* in_sizes, int n_in,
                              void* d_out, int out_size, void* d_ws, size_t ws_size,
                              hipStream_t stream) {
    (void)in_sizes; (void)n_in; (void)out_size; (void)ws_size;
    const float* te  = (const float*)d_in[0];
    const int*   spk = (const int*)  d_in[1];
    const float* Wq  = (const float*)d_in[2];
    const float* Wk  = (const float*)d_in[3];
    const float* Wv  = (const float*)d_in[4];
    const float* ipw = (const float*)d_in[5];
    const float* ipb = (const float*)d_in[6];
    const float* ow  = (const float*)d_in[7];
    const float* ob  = (const float*)d_in[8];
    const float* g1  = (const float*)d_in[9];
    const float* b1  = (const float*)d_in[10];
    const float* f1w = (const float*)d_in[11];
    const float* f1b = (const float*)d_in[12];
    const float* f2w = (const float*)d_in[13];
    const float* f2b = (const float*)d_in[14];
    const float* g2  = (const float*)d_in[15];
    const float* b2  = (const float*)d_in[16];

    float* Xout = (float*)d_out;                       // final fp32 output only

    // ws layout (bf16 region first, all byte offsets multiples of 16)
    __hip_bfloat16* wsb   = (__hip_bfloat16*)d_ws;
    __hip_bfloat16* Wq_b  = wsb;                               //   589,824
    __hip_bfloat16* ipw_b = Wq_b  + 589824;                    // 3,538,944
    __hip_bfloat16* ow_b  = ipw_b + 3538944;                   // 1,179,648
    __hip_bfloat16* f1w_b = ow_b  + 1179648;                   // 3,145,728
    __hip_bfloat16* f2w_b = f1w_b + 3145728;                   // 3,145,728
    __hip_bfloat16* Xb    = f2w_b + 3145728;                   // 6,291,456 (residual stream, bf16)
    __hip_bfloat16* SCR   = Xb    + 6291456;                   // 12,582,912 (q|k ld1536 / ffn ld2048)
    __hip_bfloat16* Vt    = SCR   + 12582912;                  // 6,291,456
    __hip_bfloat16* Ab    = Vt    + 6291456;                   // 6,291,456 (TE bf16 early / attn out)
    __hip_bfloat16* Yb    = Ab    + 6291456;                   // 6,291,456
    __hip_bfloat16* kbb   = Yb    + 6291456;                   // 98,304
    __hip_bfloat16* vbb   = kbb   + 98304;                     // 98,304
    __hip_bfloat16* Pb    = vbb   + 98304;                     // 262,144
    float* edu = (float*)(Pb + 262144);                        // 98,304 fp32

    // 1. te prep (bf16 TE into Ab + edu mean) and weight casts
    te_prep_kernel<<<(BTN * DD) / 256, 256, 0, stream>>>(te, Ab, edu);
    cast_bf16_kernel<<<(589824/4 + 255)/256, 256, 0, stream>>>(Wq, Wq_b, 589824/4);
    cast_bf16_kernel<<<(3538944/4 + 255)/256, 256, 0, stream>>>(ipw, ipw_b, 3538944/4);
    cast_bf16_kernel<<<(1179648/4 + 255)/256, 256, 0, stream>>>(ow, ow_b, 1179648/4);
    cast_bf16_kernel<<<(3145728/4 + 255)/256, 256, 0, stream>>>(f1w, f1w_b, 3145728/4);
    cast_bf16_kernel<<<(3145728/4 + 255)/256, 256, 0, stream>>>(f2w, f2w_b, 3145728/4);

    // 2. tiny k/v projections (fp32 in, bf16 out)
    gemm_abt_kernel<<<dim3(DD/GBN, BTN/GBM), 256, 0, stream>>>(edu, Wk, kbb, BTN, DD, DD);
    gemm_abt_kernel<<<dim3(DD/GBN, BTN/GBM), 256, 0, stream>>>(edu, Wv, vbb, BTN, DD, DD);

    // 3. tok = TE @ Wq^T  (bf16 out -> Xb)
    gemm_bf16_kernel<1,0,0><<<dim3(DD/128, ROWS/128), 256, 0, stream>>>(
        Ab, Wq_b, nullptr, Xb, nullptr, ROWS, DD, DD, DD);

    // 4. SAUTE: P = masked tok.v (MFMA), ctx = tok + P @ k (in place on Xb)
    saute_p_mfma_kernel<<<ROWS/64, 64, 0, stream>>>(Xb, vbb, spk, Pb);
    saute_ctx_kernel<<<ROWS/8, 256, 0, stream>>>(Xb, kbb, Pb);

    // 5. transformer layers
    for (int l = 0; l < NLAYERS; ++l) {
        const __hip_bfloat16* ipw_l = ipw_b + (size_t)l * 3 * DD * DD;
        const __hip_bfloat16* ow_l  = ow_b  + (size_t)l * DD * DD;
        const __hip_bfloat16* f1w_l = f1w_b + (size_t)l * DFF * DD;
        const __hip_bfloat16* f2w_l = f2w_b + (size_t)l * DD * DFF;

        // qkv: Q|K -> SCR (ld 1536), V -> Vt (transposed per head)
        gemm_bf16_kernel<1,0,1><<<dim3(3*DD/128, ROWS/128), 256, 0, stream>>>(
            Xb, ipw_l, ipb + (size_t)l * 3 * DD, SCR, Vt, ROWS, 3*DD, DD, 1536);
        // attention -> Ab (bf16)
        attn_mfma_kernel<<<dim3(BTN, NHEAD), 64, 0, stream>>>(SCR, Vt, Ab);
        // out proj -> Yb (bf16)
        gemm_bf16_kernel<1,0,0><<<dim3(DD/128, ROWS/128), 256, 0, stream>>>(
            Ab, ow_l, ob + (size_t)l * DD, Yb, nullptr, ROWS, DD, DD, DD);
        // Xb = LN(Xb + Yb)
        add_ln_kernel<0><<<ROWS, 192, 0, stream>>>(
            Xb, Yb, g1 + (size_t)l * DD, b1 + (size_t)l * DD, nullptr);
        // H = relu(Xb @ ff1^T + b) -> SCR (bf16, ld 2048)
        gemm_bf16_kernel<1,1,0><<<dim3(DFF/128, ROWS/128), 256, 0, stream>>>(
            Xb, f1w_l, f1b + (size_t)l * DFF, SCR, nullptr, ROWS, DFF, DD, DFF);
        // P = H @ ff2^T + b -> Yb (bf16), K=2048
        gemm_bf16_kernel<1,0,0><<<dim3(DD/128, ROWS/128), 256, 0, stream>>>(
            SCR, f2w_l, f2b + (size_t)l * DD, Yb, nullptr, ROWS, DD, DFF, DD);
        // Xb = LN(Xb + Yb); final layer writes fp32 d_out
        if (l == NLAYERS - 1)
            add_ln_kernel<1><<<ROWS, 192, 0, stream>>>(
                Xb, Yb, g2 + (size_t)l * DD, b2 + (size_t)l * DD, Xout);
        else
            add_ln_kernel<0><<<ROWS, 192, 0, stream>>>(
                Xb, Yb, g2 + (size_t)l * DD, b2 + (size_t)l * DD, nullptr);
    }
}

// Round 10
// 474.526 us; speedup vs baseline: 9.1585x; 1.1856x over previous
//
#include <hip/hip_runtime.h>
#include <hip/hip_bf16.h>

// Problem constants
#define BB 4
#define TT 32
#define LL 64
#define DD 768
#define NHEAD 12
#define DH 64
#define DFF 2048
#define NLAYERS 2
#define ROWS (BB*TT*LL)      // 8192
#define BTN  (BB*TT)         // 128

typedef __attribute__((ext_vector_type(8))) short bf16x8;
typedef __attribute__((ext_vector_type(4))) float f32x4;

// XOR swizzle for 128x32-short LDS tiles: row r (0..127), 16B chunk c (0..3).
__device__ __forceinline__ int swz(int r, int c) {
    return r * 32 + ((c ^ ((r >> 1) & 3)) << 3);
}

__device__ __forceinline__ unsigned pack_bf16(float a, float b) {
    __hip_bfloat16 h0 = __float2bfloat16(a);
    __hip_bfloat16 h1 = __float2bfloat16(b);
    return (unsigned)*reinterpret_cast<unsigned short*>(&h0) |
           ((unsigned)*reinterpret_cast<unsigned short*>(&h1) << 16);
}

__device__ __forceinline__ short bf16s(float a) {
    __hip_bfloat16 h = __float2bfloat16(a);
    return *reinterpret_cast<short*>(&h);
}

// ---------------------------------------------------------------------------
// Fused multi-tensor fp32 -> bf16 cast (7 segments, one launch).
struct CastArgs {
    const float* src[7];
    __hip_bfloat16* dst[7];
    int end[7];       // inclusive prefix sums of quad counts
};
__global__ __launch_bounds__(256) void cast_multi_kernel(CastArgs a)
{
    int q = blockIdx.x * 256 + threadIdx.x;
    if (q >= a.end[6]) return;
    int s = 0;
    while (q >= a.end[s]) ++s;
    int local = q - (s ? a.end[s - 1] : 0);
    float4 v = reinterpret_cast<const float4*>(a.src[s])[local];
    ushort4 o;
    __hip_bfloat16 h0 = __float2bfloat16(v.x);
    __hip_bfloat16 h1 = __float2bfloat16(v.y);
    __hip_bfloat16 h2 = __float2bfloat16(v.z);
    __hip_bfloat16 h3 = __float2bfloat16(v.w);
    o.x = *reinterpret_cast<unsigned short*>(&h0);
    o.y = *reinterpret_cast<unsigned short*>(&h1);
    o.z = *reinterpret_cast<unsigned short*>(&h2);
    o.w = *reinterpret_cast<unsigned short*>(&h3);
    reinterpret_cast<ushort4*>(a.dst[s])[local] = o;
}

// ---------------------------------------------------------------------------
// Fused: teb = bf16(te), edu_b = bf16(mean over L of te). One read of te.
__global__ __launch_bounds__(256) void te_prep_kernel(
    const float* __restrict__ te, __hip_bfloat16* __restrict__ teb,
    __hip_bfloat16* __restrict__ edu_b)
{
    int idx = blockIdx.x * 256 + threadIdx.x;
    int bt = idx / DD;
    int d  = idx - bt * DD;
    const float* p = te + ((size_t)bt * LL) * DD + d;
    __hip_bfloat16* q = teb + ((size_t)bt * LL) * DD + d;
    float s = 0.f;
#pragma unroll
    for (int l = 0; l < LL; ++l) {
        float v = p[(size_t)l * DD];
        s += v;
        q[(size_t)l * DD] = __float2bfloat16(v);
    }
    edu_b[idx] = __float2bfloat16(s * (1.0f / (float)LL));
}

// ---------------------------------------------------------------------------
// bf16 MFMA GEMM: reg-staged, double-buffered LDS, XOR-swizzled.
// C[M,N] = A[M,K] @ B[N,K]^T (+bias)(+relu). BM=BN=128, BK=32, 256 thr.
// QKV mode: cols < 1536 -> Cout (ld 1536); cols >= 1536 (the V third)
// stored TRANSPOSED per head into Vout[n][h][d][l].
template<int OUT_BF16, int RELU, int QKV>
__global__ __launch_bounds__(256) void gemm_bf16_kernel(
    const __hip_bfloat16* __restrict__ A,
    const __hip_bfloat16* __restrict__ B,
    const float* __restrict__ bias,
    void* __restrict__ Cout,
    __hip_bfloat16* __restrict__ Vout,
    int M, int N, int K, int ldC)
{
    __shared__ short lA[2][4096];
    __shared__ short lB[2][4096];
    const int tid  = threadIdx.x;
    const int lane = tid & 63;
    const int w    = tid >> 6;
    const int wr   = w >> 1, wc = w & 1;
    const int bm = blockIdx.y * 128;
    const int bn = blockIdx.x * 128;

    const int sr  = tid >> 2;
    const int cw  = tid & 3;
    const int sco = cw << 3;

    const int wo0 = swz(sr, cw);
    const int wo1 = swz(sr + 64, cw);
    int roA[4], roB[4];
#pragma unroll
    for (int m = 0; m < 4; ++m)
        roA[m] = swz(wr * 64 + m * 16 + (lane & 15), lane >> 4);
#pragma unroll
    for (int n = 0; n < 4; ++n)
        roB[n] = swz(wc * 64 + n * 16 + (lane & 15), lane >> 4);

    const short* Ag = reinterpret_cast<const short*>(A);
    const short* Bg = reinterpret_cast<const short*>(B);

    f32x4 acc[4][4] = {};

    bf16x8 ra0 = *reinterpret_cast<const bf16x8*>(Ag + (size_t)(bm + sr) * K + sco);
    bf16x8 ra1 = *reinterpret_cast<const bf16x8*>(Ag + (size_t)(bm + 64 + sr) * K + sco);
    bf16x8 rb0 = *reinterpret_cast<const bf16x8*>(Bg + (size_t)(bn + sr) * K + sco);
    bf16x8 rb1 = *reinterpret_cast<const bf16x8*>(Bg + (size_t)(bn + 64 + sr) * K + sco);
    *reinterpret_cast<bf16x8*>(&lA[0][wo0]) = ra0;
    *reinterpret_cast<bf16x8*>(&lA[0][wo1]) = ra1;
    *reinterpret_cast<bf16x8*>(&lB[0][wo0]) = rb0;
    *reinterpret_cast<bf16x8*>(&lB[0][wo1]) = rb1;
    __syncthreads();

    const int NT = K >> 5;
    int cur = 0;
    for (int t = 0; t < NT; ++t) {
        const bool nx = (t + 1 < NT);
        if (nx) {
            const int kn = (t + 1) << 5;
            ra0 = *reinterpret_cast<const bf16x8*>(Ag + (size_t)(bm + sr) * K + kn + sco);
            ra1 = *reinterpret_cast<const bf16x8*>(Ag + (size_t)(bm + 64 + sr) * K + kn + sco);
            rb0 = *reinterpret_cast<const bf16x8*>(Bg + (size_t)(bn + sr) * K + kn + sco);
            rb1 = *reinterpret_cast<const bf16x8*>(Bg + (size_t)(bn + 64 + sr) * K + kn + sco);
        }

        bf16x8 af[4], bfr[4];
#pragma unroll
        for (int m = 0; m < 4; ++m)
            af[m] = *reinterpret_cast<const bf16x8*>(&lA[cur][roA[m]]);
#pragma unroll
        for (int n = 0; n < 4; ++n)
            bfr[n] = *reinterpret_cast<const bf16x8*>(&lB[cur][roB[n]]);
#pragma unroll
        for (int m = 0; m < 4; ++m)
#pragma unroll
            for (int n = 0; n < 4; ++n)
                acc[m][n] = __builtin_amdgcn_mfma_f32_16x16x32_bf16(
                    af[m], bfr[n], acc[m][n], 0, 0, 0);

        if (nx) {
            *reinterpret_cast<bf16x8*>(&lA[cur ^ 1][wo0]) = ra0;
            *reinterpret_cast<bf16x8*>(&lA[cur ^ 1][wo1]) = ra1;
            *reinterpret_cast<bf16x8*>(&lB[cur ^ 1][wo0]) = rb0;
            *reinterpret_cast<bf16x8*>(&lB[cur ^ 1][wo1]) = rb1;
        }
        __syncthreads();
        cur ^= 1;
    }

    const int crow = (lane >> 4) * 4;
    const int ccol = lane & 15;
#pragma unroll
    for (int n = 0; n < 4; ++n) {
        const int col = bn + wc * 64 + n * 16 + ccol;
        const float bv = bias ? bias[col] : 0.f;
        if (QKV && col >= 1536) {
            const int hh = (col - 1536) >> 6;
            const int d  = (col - 1536) & 63;
#pragma unroll
            for (int m = 0; m < 4; ++m) {
                const int row0 = bm + wr * 64 + m * 16 + crow;
#pragma unroll
                for (int j = 0; j < 4; ++j) {
                    const int row = row0 + j;
                    const int ni = row >> 6, ll = row & 63;
                    Vout[(((size_t)ni * NHEAD + hh) << 12) + (d << 6) + ll] =
                        __float2bfloat16(acc[m][n][j] + bv);
                }
            }
        } else {
#pragma unroll
            for (int m = 0; m < 4; ++m) {
                const int row0 = bm + wr * 64 + m * 16 + crow;
#pragma unroll
                for (int j = 0; j < 4; ++j) {
                    float v = acc[m][n][j] + bv;
                    if (RELU) v = fmaxf(v, 0.f);
                    if (OUT_BF16)
                        reinterpret_cast<__hip_bfloat16*>(Cout)[(size_t)(row0 + j) * ldC + col] =
                            __float2bfloat16(v);
                    else
                        reinterpret_cast<float*>(Cout)[(size_t)(row0 + j) * ldC + col] = v;
                }
            }
        }
    }
}

// ---------------------------------------------------------------------------
// MFMA attention: one wave per (n,h). qk: (8192,1536) bf16 Q|K rows;
// vt: (128,12,64,64) bf16 V^T; out: (8192,768) bf16.
__global__ __launch_bounds__(64) void attn_mfma_kernel(
    const __hip_bfloat16* __restrict__ qk,
    const __hip_bfloat16* __restrict__ vt,
    __hip_bfloat16* __restrict__ out)
{
    const int n = blockIdx.x, h = blockIdx.y;
    const int lane = threadIdx.x;
    const int lo = lane & 15, hi = lane >> 4;
    __shared__ short pl[64 * 72];

    const short* qg = reinterpret_cast<const short*>(qk) + (size_t)(n * 64) * 1536 + h * 64;

    f32x4 acc[4][4] = {};
#pragma unroll
    for (int ks = 0; ks < 2; ++ks) {
        const int kc = ks * 32 + hi * 8;
        bf16x8 af[4], bk[4];
#pragma unroll
        for (int m = 0; m < 4; ++m)
            af[m] = *reinterpret_cast<const bf16x8*>(qg + (size_t)(m * 16 + lo) * 1536 + kc);
#pragma unroll
        for (int nn = 0; nn < 4; ++nn)
            bk[nn] = *reinterpret_cast<const bf16x8*>(qg + 768 + (size_t)(nn * 16 + lo) * 1536 + kc);
#pragma unroll
        for (int m = 0; m < 4; ++m)
#pragma unroll
            for (int nn = 0; nn < 4; ++nn)
                acc[m][nn] = __builtin_amdgcn_mfma_f32_16x16x32_bf16(
                    af[m], bk[nn], acc[m][nn], 0, 0, 0);
    }

#pragma unroll
    for (int m = 0; m < 4; ++m) {
#pragma unroll
        for (int j = 0; j < 4; ++j) {
            float s0 = acc[m][0][j] * 0.125f;
            float s1 = acc[m][1][j] * 0.125f;
            float s2 = acc[m][2][j] * 0.125f;
            float s3 = acc[m][3][j] * 0.125f;
            float mx = fmaxf(fmaxf(s0, s1), fmaxf(s2, s3));
            mx = fmaxf(mx, __shfl_xor(mx, 1));
            mx = fmaxf(mx, __shfl_xor(mx, 2));
            mx = fmaxf(mx, __shfl_xor(mx, 4));
            mx = fmaxf(mx, __shfl_xor(mx, 8));
            float e0 = __expf(s0 - mx), e1 = __expf(s1 - mx);
            float e2 = __expf(s2 - mx), e3 = __expf(s3 - mx);
            float sm = e0 + e1 + e2 + e3;
            sm += __shfl_xor(sm, 1);
            sm += __shfl_xor(sm, 2);
            sm += __shfl_xor(sm, 4);
            sm += __shfl_xor(sm, 8);
            const float inv = 1.0f / sm;
            short* pr = &pl[(m * 16 + hi * 4 + j) * 72 + lo];
            pr[0]  = bf16s(e0 * inv);
            pr[16] = bf16s(e1 * inv);
            pr[32] = bf16s(e2 * inv);
            pr[48] = bf16s(e3 * inv);
        }
    }
    __syncthreads();

    const short* vg = reinterpret_cast<const short*>(vt) + ((size_t)(n * NHEAD + h) << 12);
    f32x4 o[4][4] = {};
#pragma unroll
    for (int ks = 0; ks < 2; ++ks) {
        const int kc = ks * 32 + hi * 8;
        bf16x8 pa[4], bv[4];
#pragma unroll
        for (int m = 0; m < 4; ++m)
            pa[m] = *reinterpret_cast<const bf16x8*>(&pl[(m * 16 + lo) * 72 + kc]);
#pragma unroll
        for (int nn = 0; nn < 4; ++nn)
            bv[nn] = *reinterpret_cast<const bf16x8*>(vg + (nn * 16 + lo) * 64 + kc);
#pragma unroll
        for (int m = 0; m < 4; ++m)
#pragma unroll
            for (int nn = 0; nn < 4; ++nn)
                o[m][nn] = __builtin_amdgcn_mfma_f32_16x16x32_bf16(
                    pa[m], bv[nn], o[m][nn], 0, 0, 0);
    }

#pragma unroll
    for (int m = 0; m < 4; ++m)
#pragma unroll
        for (int nn = 0; nn < 4; ++nn)
#pragma unroll
            for (int j = 0; j < 4; ++j)
                out[(size_t)(n * 64 + m * 16 + hi * 4 + j) * DD + h * 64 + nn * 16 + lo] =
                    __float2bfloat16(o[m][nn][j]);
}

// ---------------------------------------------------------------------------
// SAUTE part 1 (MFMA): P[row][u] = mask * (tok[row,:].v[b,u,:]).
// One wave per 64-row group. KV: (128,1536) bf16, v = cols 768..1535.
__global__ __launch_bounds__(64) void saute_p_mfma_kernel(
    const __hip_bfloat16* __restrict__ Xb,
    const __hip_bfloat16* __restrict__ KV,
    const int* __restrict__ spk,
    __hip_bfloat16* __restrict__ P)
{
    const int lane = threadIdx.x;
    const int lo = lane & 15, hi = lane >> 4;
    const int row0 = blockIdx.x * 64;
    const int bt = row0 >> 6;
    const int b  = bt >> 5, t = bt & 31;

    const short* Ag = reinterpret_cast<const short*>(Xb) + (size_t)row0 * DD;
    const short* Bg = reinterpret_cast<const short*>(KV) + (size_t)(b * TT) * 1536 + 768;

    f32x4 acc[4][2] = {};
    for (int ks = 0; ks < 24; ++ks) {
        const int kc = ks * 32 + hi * 8;
        bf16x8 af[4], bv[2];
#pragma unroll
        for (int m = 0; m < 4; ++m)
            af[m] = *reinterpret_cast<const bf16x8*>(Ag + (size_t)(m * 16 + lo) * DD + kc);
#pragma unroll
        for (int nn = 0; nn < 2; ++nn)
            bv[nn] = *reinterpret_cast<const bf16x8*>(Bg + (size_t)(nn * 16 + lo) * 1536 + kc);
#pragma unroll
        for (int m = 0; m < 4; ++m)
#pragma unroll
            for (int nn = 0; nn < 2; ++nn)
                acc[m][nn] = __builtin_amdgcn_mfma_f32_16x16x32_bf16(
                    af[m], bv[nn], acc[m][nn], 0, 0, 0);
    }

    const int st = spk[bt];
#pragma unroll
    for (int nn = 0; nn < 2; ++nn) {
        const int u = nn * 16 + lo;
        const bool mk = (u <= t) && (spk[b * TT + u] == st);
#pragma unroll
        for (int m = 0; m < 4; ++m)
#pragma unroll
            for (int j = 0; j < 4; ++j) {
                const int row = row0 + m * 16 + hi * 4 + j;
                P[(size_t)row * 32 + u] =
                    mk ? __float2bfloat16(acc[m][nn][j]) : __float2bfloat16(0.f);
            }
    }
}

// ---------------------------------------------------------------------------
// SAUTE part 2: ctx = tok + P @ k, in place on bf16 Xb.
// KV: (128,1536) bf16, k = cols 0..767 (row stride 768 uint pairs).
__global__ __launch_bounds__(256) void saute_ctx_kernel(
    __hip_bfloat16* __restrict__ Xb,
    const __hip_bfloat16* __restrict__ KV,
    const __hip_bfloat16* __restrict__ P)
{
    __shared__ unsigned kls[32 * 384];      // 49.2 KB bf16 pairs
    __shared__ float pls[8 * 32];
    const int row0 = blockIdx.x * 8;
    const int b = row0 >> 11;
    const int tid = threadIdx.x;

    const unsigned* k2 = reinterpret_cast<const unsigned*>(KV) + (size_t)(b * TT) * 768;
    for (int i = tid; i < 32 * 384; i += 256) {
        int u = i / 384, j = i - u * 384;
        kls[i] = k2[u * 768 + j];
    }
    pls[tid] = __bfloat162float(P[(size_t)row0 * 32 + tid]);
    __syncthreads();

    const int r = tid >> 5;
    const int l32 = tid & 31;
    unsigned* xrow = reinterpret_cast<unsigned*>(Xb + (size_t)(row0 + r) * DD);

    float2 acc[12];
#pragma unroll
    for (int c = 0; c < 12; ++c) {
        unsigned pk = xrow[l32 + 32 * c];
        acc[c].x = __uint_as_float(pk << 16);
        acc[c].y = __uint_as_float(pk & 0xffff0000u);
    }
    for (int u = 0; u < 32; ++u) {
        const float pv = pls[r * 32 + u];
        const unsigned* kr = &kls[u * 384];
#pragma unroll
        for (int c = 0; c < 12; ++c) {
            unsigned pk = kr[l32 + 32 * c];
            acc[c].x = fmaf(pv, __uint_as_float(pk << 16),          acc[c].x);
            acc[c].y = fmaf(pv, __uint_as_float(pk & 0xffff0000u), acc[c].y);
        }
    }
#pragma unroll
    for (int c = 0; c < 12; ++c)
        xrow[l32 + 32 * c] = pack_bf16(acc[c].x, acc[c].y);
}

// ---------------------------------------------------------------------------
// LayerNorm over bf16 residual: xb = bf16(LN(xb + y)); FINAL also writes fp32.
template<int FINAL>
__global__ __launch_bounds__(192) void add_ln_kernel(
    __hip_bfloat16* __restrict__ xb, const __hip_bfloat16* __restrict__ y,
    const float* __restrict__ g, const float* __restrict__ bb,
    float* __restrict__ xf)
{
    const int row = blockIdx.x;
    const int tid = threadIdx.x;
    __shared__ float red[3];
    __shared__ float stat[2];
    const size_t base = (size_t)row * DD + tid * 4;

    uint2 xv = *reinterpret_cast<const uint2*>(xb + base);
    uint2 yv = *reinterpret_cast<const uint2*>(y + base);
    float v[4];
    v[0] = __uint_as_float(xv.x << 16)         + __uint_as_float(yv.x << 16);
    v[1] = __uint_as_float(xv.x & 0xffff0000u) + __uint_as_float(yv.x & 0xffff0000u);
    v[2] = __uint_as_float(xv.y << 16)         + __uint_as_float(yv.y << 16);
    v[3] = __uint_as_float(xv.y & 0xffff0000u) + __uint_as_float(yv.y & 0xffff0000u);

    float s = v[0] + v[1] + v[2] + v[3];
#pragma unroll
    for (int off = 32; off > 0; off >>= 1) s += __shfl_down(s, off);
    if ((tid & 63) == 0) red[tid >> 6] = s;
    __syncthreads();
    if (tid == 0) stat[0] = (red[0] + red[1] + red[2]) * (1.0f / (float)DD);
    __syncthreads();
    const float mu = stat[0];

    float d[4];
    float q = 0.f;
#pragma unroll
    for (int i = 0; i < 4; ++i) { d[i] = v[i] - mu; q += d[i] * d[i]; }
    __syncthreads();
#pragma unroll
    for (int off = 32; off > 0; off >>= 1) q += __shfl_down(q, off);
    if ((tid & 63) == 0) red[tid >> 6] = q;
    __syncthreads();
    if (tid == 0) stat[1] = (red[0] + red[1] + red[2]) * (1.0f / (float)DD);
    __syncthreads();
    const float rstd = rsqrtf(stat[1] + 1e-5f);

    float o[4];
#pragma unroll
    for (int i = 0; i < 4; ++i)
        o[i] = d[i] * rstd * g[tid * 4 + i] + bb[tid * 4 + i];

    if (FINAL) {
        float4 f4 = make_float4(o[0], o[1], o[2], o[3]);
        *reinterpret_cast<float4*>(xf + base) = f4;
    } else {
        uint2 ov;
        ov.x = pack_bf16(o[0], o[1]);
        ov.y = pack_bf16(o[2], o[3]);
        *reinterpret_cast<uint2*>(xb + base) = ov;
    }
}

// ---------------------------------------------------------------------------
extern "C" void kernel_launch(void* const* d_in, const int* in_sizes, int n_in,
                              void* d_out, int out_size, void* d_ws, size_t ws_size,
                              hipStream_t stream) {
    (void)in_sizes; (void)n_in; (void)out_size; (void)ws_size;
    const float* te  = (const float*)d_in[0];
    const int*   spk = (const int*)  d_in[1];
    const float* Wq  = (const float*)d_in[2];
    const float* Wk  = (const float*)d_in[3];
    const float* Wv  = (const float*)d_in[4];
    const float* ipw = (const float*)d_in[5];
    const float* ipb = (const float*)d_in[6];
    const float* ow  = (const float*)d_in[7];
    const float* ob  = (const float*)d_in[8];
    const float* g1  = (const float*)d_in[9];
    const float* b1  = (const float*)d_in[10];
    const float* f1w = (const float*)d_in[11];
    const float* f1b = (const float*)d_in[12];
    const float* f2w = (const float*)d_in[13];
    const float* f2b = (const float*)d_in[14];
    const float* g2  = (const float*)d_in[15];
    const float* b2  = (const float*)d_in[16];

    float* Xout = (float*)d_out;

    // ws layout (bf16, all byte offsets multiples of 16)
    __hip_bfloat16* wsb   = (__hip_bfloat16*)d_ws;
    __hip_bfloat16* Wq_b  = wsb;                               //   589,824
    __hip_bfloat16* ipw_b = Wq_b  + 589824;                    // 3,538,944
    __hip_bfloat16* ow_b  = ipw_b + 3538944;                   // 1,179,648
    __hip_bfloat16* f1w_b = ow_b  + 1179648;                   // 3,145,728
    __hip_bfloat16* f2w_b = f1w_b + 3145728;                   // 3,145,728
    __hip_bfloat16* Xb    = f2w_b + 3145728;                   // 6,291,456 (bf16 residual)
    __hip_bfloat16* SCR   = Xb    + 6291456;                   // 18,874,368 combined region:
                                                               //   q|k (ld1536, 12.58M) + Vt (6.29M);
                                                               //   ff1 hidden (ld2048, 16.78M) overruns
                                                               //   into Vt AFTER attn consumed it (safe);
                                                               //   Wkv_b aliases base before layer 1.
    __hip_bfloat16* Vt    = SCR   + 12582912;
    __hip_bfloat16* Wkv_b = SCR;                               // 1,179,648 (pre-layer alias)
    __hip_bfloat16* Ab    = SCR   + 18874368;                  // 6,291,456 (TE bf16 early / attn out)
    __hip_bfloat16* Yb    = Ab    + 6291456;                   // 6,291,456
    __hip_bfloat16* KV    = Yb    + 6291456;                   // 196,608 (128 x 1536: k|v)
    __hip_bfloat16* Pb    = KV    + 196608;                    // 262,144
    __hip_bfloat16* edu_b = Pb    + 262144;                    // 98,304

    // 1. te prep (TE bf16 into Ab + bf16 edu)
    te_prep_kernel<<<(BTN * DD) / 256, 256, 0, stream>>>(te, Ab, edu_b);

    // 2. all weight casts in one launch (Wk|Wv land contiguous in Wkv_b)
    CastArgs ca;
    ca.src[0] = Wq;  ca.dst[0] = Wq_b;
    ca.src[1] = ipw; ca.dst[1] = ipw_b;
    ca.src[2] = ow;  ca.dst[2] = ow_b;
    ca.src[3] = f1w; ca.dst[3] = f1w_b;
    ca.src[4] = f2w; ca.dst[4] = f2w_b;
    ca.src[5] = Wk;  ca.dst[5] = Wkv_b;
    ca.src[6] = Wv;  ca.dst[6] = Wkv_b + 589824;
    int quads[7] = {589824/4, 3538944/4, 1179648/4, 3145728/4, 3145728/4, 589824/4, 589824/4};
    int acc = 0;
    for (int i = 0; i < 7; ++i) { acc += quads[i]; ca.end[i] = acc; }
    cast_multi_kernel<<<(acc + 255) / 256, 256, 0, stream>>>(ca);

    // 3. k|v projection: KV = edu_b @ (Wk|Wv)^T  (M=128, N=1536, K=768)
    gemm_bf16_kernel<1,0,0><<<dim3(1536/128, 1), 256, 0, stream>>>(
        edu_b, Wkv_b, nullptr, KV, nullptr, BTN, 1536, DD, 1536);

    // 4. tok = TE @ Wq^T  (bf16 out -> Xb)
    gemm_bf16_kernel<1,0,0><<<dim3(DD/128, ROWS/128), 256, 0, stream>>>(
        Ab, Wq_b, nullptr, Xb, nullptr, ROWS, DD, DD, DD);

    // 5. SAUTE: P = masked tok.v (MFMA), ctx = tok + P @ k (in place on Xb)
    saute_p_mfma_kernel<<<ROWS/64, 64, 0, stream>>>(Xb, KV, spk, Pb);
    saute_ctx_kernel<<<ROWS/8, 256, 0, stream>>>(Xb, KV, Pb);

    // 6. transformer layers
    for (int l = 0; l < NLAYERS; ++l) {
        const __hip_bfloat16* ipw_l = ipw_b + (size_t)l * 3 * DD * DD;
        const __hip_bfloat16* ow_l  = ow_b  + (size_t)l * DD * DD;
        const __hip_bfloat16* f1w_l = f1w_b + (size_t)l * DFF * DD;
        const __hip_bfloat16* f2w_l = f2w_b + (size_t)l * DD * DFF;

        // qkv: Q|K -> SCR (ld 1536), V -> Vt (transposed per head)
        gemm_bf16_kernel<1,0,1><<<dim3(3*DD/128, ROWS/128), 256, 0, stream>>>(
            Xb, ipw_l, ipb + (size_t)l * 3 * DD, SCR, Vt, ROWS, 3*DD, DD, 1536);
        // attention -> Ab (bf16)
        attn_mfma_kernel<<<dim3(BTN, NHEAD), 64, 0, stream>>>(SCR, Vt, Ab);
        // out proj -> Yb (bf16)
        gemm_bf16_kernel<1,0,0><<<dim3(DD/128, ROWS/128), 256, 0, stream>>>(
            Ab, ow_l, ob + (size_t)l * DD, Yb, nullptr, ROWS, DD, DD, DD);
        // Xb = LN(Xb + Yb)
        add_ln_kernel<0><<<ROWS, 192, 0, stream>>>(
            Xb, Yb, g1 + (size_t)l * DD, b1 + (size_t)l * DD, nullptr);
        // H = relu(Xb @ ff1^T + b) -> SCR (bf16, ld 2048)
        gemm_bf16_kernel<1,1,0><<<dim3(DFF/128, ROWS/128), 256, 0, stream>>>(
            Xb, f1w_l, f1b + (size_t)l * DFF, SCR, nullptr, ROWS, DFF, DD, DFF);
        // P = H @ ff2^T + b -> Yb (bf16), K=2048
        gemm_bf16_kernel<1,0,0><<<dim3(DD/128, ROWS/128), 256, 0, stream>>>(
            SCR, f2w_l, f2b + (size_t)l * DD, Yb, nullptr, ROWS, DD, DFF, DD);
        // Xb = LN(Xb + Yb); final layer writes fp32 d_out
        if (l == NLAYERS - 1)
            add_ln_kernel<1><<<ROWS, 192, 0, stream>>>(
                Xb, Yb, g2 + (size_t)l * DD, b2 + (size_t)l * DD, Xout);
        else
            add_ln_kernel<0><<<ROWS, 192, 0, stream>>>(
                Xb, Yb, g2 + (size_t)l * DD, b2 + (size_t)l * DD, nullptr);
    }
}